// Round 10
// baseline (145.773 us; speedup 1.0000x reference)
//
#include <hip/hip_runtime.h>
#include <cstdint>
#include <cstddef>

// ---------------------------------------------------------------------------
// HierarchicalQueryMatcher, N=2048, W=64, D=512.
//   LN1(x)@w1+b1 = rs*(A[n,:]+B[w,:]) - rs*mu*G + C
//   h2 = gelu(h) @ w2 ; y = h2 + q[n] + b2
//   out = 16 * dot(LN2(y), cmhat)/max(||LN2(y)||,eps)
// Linear-in-h2 sums folded into extra GEMM cols (M6 = w2@cmhg^T, v1,v3,v4);
// quadratic sums (S2,S5) streamed in the MFMA epilogue. h2-GEMM in INT8.
// Round 10: 4 af sets per wave (1 n x 4 w-tiles, 128 i8 regs -> AGPR-able).
// We're register-pinned in the 2-waves/SIMD tier (129-256) either way, so
// spend the tier: fragment LDS reads amortize 4x (per-CU LDS traffic halves).
// 256 blocks (one pass). G/C read from global (L1 broadcast). r6 ring kept.
// ---------------------------------------------------------------------------

#define NQ 2048
#define NWC 64
#define DD 512
#define NCHUNK 19
#define SA_CONST (4.0f / 127.0f)
#define MAGICF 12582912.0f

typedef __attribute__((ext_vector_type(8))) short short8;
typedef __attribute__((ext_vector_type(8))) unsigned short ushort8;
typedef __attribute__((ext_vector_type(4))) float f32x4;
typedef __attribute__((ext_vector_type(4))) int i32v4;
typedef __attribute__((ext_vector_type(4))) unsigned u32x4;

__device__ __forceinline__ unsigned short f2bf(float f) {
  unsigned u = __float_as_uint(f);
  u += 0x7fffu + ((u >> 16) & 1u);
  return (unsigned short)(u >> 16);
}

__device__ __forceinline__ unsigned cvtpk2(float lo, float hi) {
  unsigned r;
  asm("v_cvt_pk_bf16_f32 %0, %1, %2" : "=v"(r) : "v"(lo), "v"(hi));
  return r;
}

__device__ __forceinline__ float bf2f(unsigned short u) {
  return __uint_as_float(((unsigned)u) << 16);
}

// gelu(h)*31.75, clamped to [-127,127] via med3.
__device__ __forceinline__ float gelu31(float h) {
  float h2 = h * h;
  float zn = h * fmaf(h2, -0.10295890518f, -2.30221607f); // -z*log2(e)
  float t = exp2f(zn);
  float r = __builtin_amdgcn_rcpf(1.0f + t);
  float gv = (h * 31.75f) * r;
  return __builtin_amdgcn_fmed3f(gv, -127.0f, 127.0f);
}

// 4 clamped floats -> packed i8 dword via magic-round + byte_perm (7 ops).
__device__ __forceinline__ unsigned quad_i8(float a, float b, float c, float d) {
  unsigned u0 = __float_as_uint(a + MAGICF);
  unsigned u1 = __float_as_uint(b + MAGICF);
  unsigned u2 = __float_as_uint(c + MAGICF);
  unsigned u3 = __float_as_uint(d + MAGICF);
  unsigned s1 = __byte_perm(u0, u1, 0x0040);
  unsigned s2 = __byte_perm(u2, u3, 0x0040);
  return __byte_perm(s1, s2, 0x5410);
}

__device__ __forceinline__ float wred(float v) {
#pragma unroll
  for (int m = 1; m < 64; m <<= 1) v += __shfl_xor(v, m, 64);
  return v;
}

__device__ __forceinline__ int sel4i(i32v4 v, int r) {
  int x = (r & 1) ? v[1] : v[0];
  int y = (r & 1) ? v[3] : v[2];
  return (r & 2) ? y : x;
}

// ---------------- k_prep: all O(N*D) precompute in one launch ----------------
__global__ __launch_bounds__(256) void k_prep(
    const float* __restrict__ q, const float* __restrict__ cm,
    const float* __restrict__ g1, const float* __restrict__ be1,
    const float* __restrict__ w1, const float* __restrict__ w2,
    const float* __restrict__ g2, const float* __restrict__ be2,
    const float* __restrict__ b2,
    float* __restrict__ Sq, float* __restrict__ SSq, float* __restrict__ qst,
    float* __restrict__ Sc, float* __restrict__ SSc, float* __restrict__ cmhg,
    float* __restrict__ c1, float* __restrict__ c2, float* __restrict__ c3,
    float* __restrict__ Gp, float* __restrict__ Cp, float* __restrict__ V,
    float* __restrict__ gg, float* __restrict__ scal) {
  const int b = blockIdx.x, tid = threadIdx.x;
  const int wv = tid >> 6, l = tid & 63;
  __shared__ float shr[3][4];
  __shared__ float s_inv;

  if (b < 256) {
    f32x4 b20 = *(const f32x4*)(b2 + l * 8);
    f32x4 b21 = *(const f32x4*)(b2 + l * 8 + 4);
    f32x4 g20 = *(const f32x4*)(g2 + l * 8);
    f32x4 g21 = *(const f32x4*)(g2 + l * 8 + 4);
    f32x4 e20 = *(const f32x4*)(be2 + l * 8);
    f32x4 e21 = *(const f32x4*)(be2 + l * 8 + 4);
#pragma unroll
    for (int rr = 0; rr < 2; ++rr) {
      int r = b * 8 + wv * 2 + rr;
      const float* row = q + (size_t)r * DD;
      f32x4 q0 = *(const f32x4*)(row + l * 8);
      f32x4 q1 = *(const f32x4*)(row + l * 8 + 4);
      float s0 = 0, s1 = 0, s2 = 0, s3 = 0, s4 = 0;
#pragma unroll
      for (int i = 0; i < 4; ++i) {
        float v = q0[i]; s0 += v; s1 = fmaf(v, v, s1);
        float qb = v + b20[i], g = g20[i];
        s2 += qb; s3 = fmaf(qb, g * g, s3); s4 = fmaf(qb, g * e20[i], s4);
        v = q1[i]; s0 += v; s1 = fmaf(v, v, s1);
        qb = v + b21[i]; g = g21[i];
        s2 += qb; s3 = fmaf(qb, g * g, s3); s4 = fmaf(qb, g * e21[i], s4);
      }
      s0 = wred(s0); s1 = wred(s1); s2 = wred(s2); s3 = wred(s3); s4 = wred(s4);
      if (l == 0) {
        Sq[r] = s0; SSq[r] = s1;
        qst[r * 4 + 0] = s2; qst[r * 4 + 1] = s3; qst[r * 4 + 2] = s4;
      }
    }
  } else if (b < 320) {
    int w = b - 256;
    const float* row = cm + (size_t)w * DD;
    float sm = 0.f, ss = 0.f;
    for (int c = tid; c < DD; c += 256) { float v = row[c]; sm += v; ss = fmaf(v, v, ss); }
    sm = wred(sm); ss = wred(ss);
    if (l == 0) { shr[0][wv] = sm; shr[1][wv] = ss; }
    __syncthreads();
    if (tid == 0) {
      float smt = shr[0][0] + shr[0][1] + shr[0][2] + shr[0][3];
      float sst = shr[1][0] + shr[1][1] + shr[1][2] + shr[1][3];
      Sc[w] = smt; SSc[w] = sst;
      s_inv = 1.0f / fmaxf(sqrtf(sst), 1e-12f);
    }
    __syncthreads();
    float inv = s_inv;
    float a = 0.f, bs = 0.f, d = 0.f;
    for (int c = tid; c < DD; c += 256) {
      float ch = row[c] * inv;
      float gv = g2[c];
      float gch = gv * ch;
      cmhg[(size_t)w * DD + c] = gch;
      a += gch;
      bs = fmaf(be2[c], ch, bs);
      d = fmaf(b2[c], gch, d);
    }
    a = wred(a); bs = wred(bs); d = wred(d);
    __syncthreads();
    if (l == 0) { shr[0][wv] = a; shr[1][wv] = bs; shr[2][wv] = d; }
    __syncthreads();
    if (tid == 0) {
      c1[w] = shr[0][0] + shr[0][1] + shr[0][2] + shr[0][3];
      c2[w] = shr[1][0] + shr[1][1] + shr[1][2] + shr[1][3];
      c3[w] = shr[2][0] + shr[2][1] + shr[2][2] + shr[2][3];
    }
  } else if (b < 336) {
    int bk = b - 320, k0 = bk * 64;
#pragma unroll
    for (int jh = 0; jh < 2; ++jh) {
      int j = tid + jh * 256;
      float g = 0.f, c = 0.f;
#pragma unroll 4
      for (int k = 0; k < 64; ++k) {
        float wv4 = w1[(size_t)(k0 + k) * DD + j];
        g = fmaf(g1[k0 + k], wv4, g);
        c = fmaf(be1[k0 + k], wv4, c);
      }
      Gp[(size_t)bk * DD + j] = g;
      Cp[(size_t)bk * DD + j] = c;
    }
  } else if (b < 400) {
    int bb = b - 336;
    f32x4 g20 = *(const f32x4*)(g2 + l * 8);
    f32x4 g21 = *(const f32x4*)(g2 + l * 8 + 4);
    f32x4 e20 = *(const f32x4*)(be2 + l * 8);
    f32x4 e21 = *(const f32x4*)(be2 + l * 8 + 4);
#pragma unroll
    for (int rr = 0; rr < 2; ++rr) {
      int k = bb * 8 + wv * 2 + rr;
      const float* row = w2 + (size_t)k * DD;
      f32x4 w0 = *(const f32x4*)(row + l * 8);
      f32x4 w1v = *(const f32x4*)(row + l * 8 + 4);
      float s1 = 0, s3 = 0, s4 = 0;
#pragma unroll
      for (int i = 0; i < 4; ++i) {
        float w = w0[i], g = g20[i];
        s1 += w; s3 = fmaf(w, g * g, s3); s4 = fmaf(w, g * e20[i], s4);
        w = w1v[i]; g = g21[i];
        s1 += w; s3 = fmaf(w, g * g, s3); s4 = fmaf(w, g * e21[i], s4);
      }
      s1 = wred(s1); s3 = wred(s3); s4 = wred(s4);
      if (l == 0) {
        V[k * 4 + 0] = s1; V[k * 4 + 1] = s3; V[k * 4 + 2] = s4; V[k * 4 + 3] = 0.f;
      }
    }
  } else {
    float a0 = 0, a1 = 0, a2 = 0;
    for (int c = tid; c < DD; c += 256) {
      float g = g2[c], be = be2[c];
      gg[c] = g * g;
      a0 = fmaf(g, g, a0); a1 = fmaf(g, be, a1); a2 = fmaf(be, be, a2);
    }
    a0 = wred(a0); a1 = wred(a1); a2 = wred(a2);
    if (l == 0) { shr[0][wv] = a0; shr[1][wv] = a1; shr[2][wv] = a2; }
    __syncthreads();
    if (tid == 0) {
      scal[0] = shr[0][0] + shr[0][1] + shr[0][2] + shr[0][3];
      scal[1] = shr[1][0] + shr[1][1] + shr[1][2] + shr[1][3];
      scal[2] = shr[2][0] + shr[2][1] + shr[2][2] + shr[2][3];
    }
  }
}

// ---------------- k_pack1: PW1T + PW1B + PCT (bf16 GEMM operands) -------------
__global__ __launch_bounds__(512) void k_pack1(
    const float* __restrict__ w1, const float* __restrict__ ln1w,
    const float* __restrict__ cmhg,
    unsigned short* __restrict__ PW1T, unsigned short* __restrict__ PW1B,
    unsigned short* __restrict__ PCT) {
  int b = blockIdx.x;
  if (b < 128) {
    int roff = (b < 64) ? 0 : 512;
    unsigned short* out = (b < 64) ? PW1T : PW1B;
    int tid = (b & 63) * 512 + threadIdx.x;
    int l = tid & 63, t = (tid >> 6) & 15, ct = tid >> 10, g = l >> 4;
    int col = (ct << 4) + (l & 15);
    ushort8 o;
#pragma unroll
    for (int i = 0; i < 8; ++i) {
      int k = t * 32 + g * 8 + i;
      o[i] = f2bf(w1[(size_t)(roff + k) * DD + col] * ln1w[roff + k]);
    }
    *(ushort8*)(out + (size_t)tid * 8) = o;
  } else {
    int tid = (b - 128) * 512 + threadIdx.x;
    int l = tid & 63, t = (tid >> 6) & 15, g = l >> 4;
    int col = ((tid >> 10) << 4) + (l & 15);
    ushort8 o;
#pragma unroll
    for (int i = 0; i < 8; ++i) {
      int k = t * 32 + g * 8 + i;
      o[i] = f2bf(cmhg[(size_t)col * DD + k]);
    }
    *(ushort8*)(PCT + (size_t)tid * 8) = o;
  }
}

// ---------------- k_gemms: 4 bf16 GEMM jobs in one dispatch -------------------
__global__ __launch_bounds__(256) void k_gemms(
    const float* __restrict__ q, const float* __restrict__ cm,
    const float* __restrict__ w2,
    const unsigned short* __restrict__ PW1T, const unsigned short* __restrict__ PW1B,
    const unsigned short* __restrict__ PCT,
    float* __restrict__ A, unsigned short* __restrict__ Bwb,
    float* __restrict__ QC, float* __restrict__ M6) {
  int b = blockIdx.x;
  const float* X; const unsigned short* PW; void* Out;
  int bx, by, ostride, obf;
  if (b < 256)      { X = q;  PW = PW1T; Out = A;    bx = b & 7;   by = b >> 3;  ostride = DD;  obf = 0; }
  else if (b < 264) { X = cm; PW = PW1B; Out = Bwb;  bx = b - 256; by = 0;       ostride = DD;  obf = 1; }
  else if (b < 296) { X = q;  PW = PCT;  Out = QC;   bx = 0;       by = b - 264; ostride = NWC; obf = 0; }
  else              { X = w2; PW = PCT;  Out = M6;   bx = 0;       by = b - 296; ostride = NWC; obf = 0; }

  int l = threadIdx.x & 63;
  int wv = threadIdx.x >> 6;
  int lr = l & 15, g = l >> 4;
  int r0 = by * 64 + wv * 16;
  int cb0 = bx * 4;
  f32x4 acc[4] = {{0,0,0,0},{0,0,0,0},{0,0,0,0},{0,0,0,0}};
  const float* xrow = X + (size_t)(r0 + lr) * DD;
#pragma unroll
  for (int t = 0; t < 16; ++t) {
    int kb = t * 32 + g * 8;
    f32x4 x0 = *(const f32x4*)(xrow + kb);
    f32x4 x1 = *(const f32x4*)(xrow + kb + 4);
    union { short8 s; unsigned u[4]; } af;
    af.u[0] = cvtpk2(x0[0], x0[1]);
    af.u[1] = cvtpk2(x0[2], x0[3]);
    af.u[2] = cvtpk2(x1[0], x1[1]);
    af.u[3] = cvtpk2(x1[2], x1[3]);
#pragma unroll
    for (int c = 0; c < 4; ++c) {
      short8 bf = *(const short8*)(PW + (size_t)(((cb0 + c) * 16 + t) * 64 + l) * 8);
      acc[c] = __builtin_amdgcn_mfma_f32_16x16x32_bf16(af.s, bf, acc[c], 0, 0, 0);
    }
  }
#pragma unroll
  for (int c = 0; c < 4; ++c)
#pragma unroll
    for (int r = 0; r < 4; ++r) {
      size_t idx = (size_t)(r0 + g * 4 + r) * ostride + (cb0 + c) * 16 + lr;
      float v = acc[c][r];
      if (obf) ((unsigned short*)Out)[idx] = f2bf(v);
      else     ((float*)Out)[idx] = v;
    }
}

// ---------------- k_pack2: i8 W2X + scales + PBw + G/C ------------------------
__global__ __launch_bounds__(512) void k_pack2(
    const float* __restrict__ w2, const float* __restrict__ M6,
    const float* __restrict__ V, const unsigned short* __restrict__ Bwb,
    const float* __restrict__ Gp, const float* __restrict__ Cp,
    const float* __restrict__ b1,
    signed char* __restrict__ PW2X, unsigned short* __restrict__ PBw,
    float* __restrict__ G, float* __restrict__ C, float* __restrict__ Scales) {
  int b = blockIdx.x, tx = threadIdx.x;
  __shared__ float red[16][33];
  __shared__ float sinv[16];
  if (b < 38) {
    int ct = b;
    int t8 = tx >> 6, l = tx & 63, g4 = l >> 4, lc = l & 15;
    int col = ct * 16 + lc;
    float v[16]; float lmax = 0.f;
#pragma unroll
    for (int i = 0; i < 16; ++i) {
      int k = t8 * 64 + g4 * 16 + i;
      float x;
      if (col < 512)      x = w2[(size_t)k * DD + col];
      else if (col < 576) x = M6[(size_t)k * 64 + (col - 512)];
      else { int cv = col - 576; x = (cv < 3) ? V[k * 4 + cv] : 0.f; }
      v[i] = x; lmax = fmaxf(lmax, fabsf(x));
    }
    red[lc][t8 * 4 + g4] = lmax;
    __syncthreads();
    if (tx < 16) {
      float m = 0.f;
#pragma unroll
      for (int j = 0; j < 32; ++j) m = fmaxf(m, red[tx][j]);
      float sc = fmaxf(m, 1e-20f) * (1.0f / 127.0f);
      Scales[ct * 16 + tx] = sc;
      sinv[tx] = 1.0f / sc;
    }
    __syncthreads();
    float inv = sinv[lc];
    u32x4 d;
#pragma unroll
    for (int j = 0; j < 4; ++j) {
      unsigned u = 0;
#pragma unroll
      for (int e = 0; e < 4; ++e) {
        float qv = v[j * 4 + e] * inv;
        qv = fminf(fmaxf(qv, -127.f), 127.f);
        int iq = (int)rintf(qv);
        u |= ((unsigned)(iq & 255)) << (8 * e);
      }
      d[j] = u;
    }
    *(u32x4*)(PW2X + (size_t)ct * 8192 + (size_t)(t8 * 64 + l) * 16) = d;
  } else if (b < 42) {
    int slot = (b - 38) * 512 + tx;  // 2048 slots
    int wt = slot >> 9, r = slot & 511, t8 = r >> 6, l = r & 63;
    int w = wt * 16 + (l & 15);
    int kb = t8 * 64 + (l >> 4) * 16;
    ushort8 o0, o1;
#pragma unroll
    for (int i = 0; i < 8; ++i) {
      o0[i] = Bwb[(size_t)w * DD + kb + i];
      o1[i] = Bwb[(size_t)w * DD + kb + 8 + i];
    }
    *(ushort8*)(PBw + (size_t)slot * 16) = o0;
    *(ushort8*)(PBw + (size_t)slot * 16 + 8) = o1;
  } else {
    int c = tx;
    float g = 0.f, cc2 = 0.f;
#pragma unroll
    for (int p = 0; p < 16; ++p) { g += Gp[p * DD + c]; cc2 += Cp[p * DD + c]; }
    G[c] = g; C[c] = cc2 + b1[c];
  }
}

// ---------------- fused main kernel: 4 af sets/wave, counted-vmcnt ring -------

__device__ __forceinline__ void async16(const void* g, void* lds) {
  __builtin_amdgcn_global_load_lds(
      (const __attribute__((address_space(1))) void*)(uintptr_t)g,
      (__attribute__((address_space(3))) void*)(unsigned int)(uintptr_t)lds,
      16, 0, 0);
}

__global__ __launch_bounds__(512, 2) void k_main(
    const float* __restrict__ Afull, const unsigned short* __restrict__ PBw,
    const float* __restrict__ Gv, const float* __restrict__ Cc,
    const float* __restrict__ q, const float* __restrict__ b2,
    const float* __restrict__ gg, const float* __restrict__ qst,
    const float* __restrict__ QC, const float* __restrict__ c1v,
    const float* __restrict__ c2v, const float* __restrict__ c3v,
    const float* __restrict__ Sq, const float* __restrict__ SSq,
    const float* __restrict__ Sc, const float* __restrict__ SSc,
    const float* __restrict__ scal, const signed char* __restrict__ PW2X,
    const float* __restrict__ Scales, float* __restrict__ out) {

  __shared__ __align__(16) float sA[8][DD], sQB[8][DD];
  __shared__ __align__(16) float sGG[DD], sSC[608];
  __shared__ __align__(16) signed char sW[3 * 16384];   // 3x16KB i8 chunk ring

  const int tid = threadIdx.x;
  const int wv = tid >> 6, l = tid & 63;
  const int g = l >> 4, lr = l & 15;
  const int n0 = blockIdx.x * 8;
  const int n = n0 + wv;               // one n per wave

  // ---- stage block-wide LDS state ----
  sGG[tid] = gg[tid];
  for (int i = tid; i < 608; i += 512) sSC[i] = Scales[i] * SA_CONST;
  float b2v = b2[tid];
#pragma unroll
  for (int s = 0; s < 8; ++s) {
    sA[s][tid]  = Afull[(size_t)(n0 + s) * DD + tid];
    sQB[s][tid] = q[(size_t)(n0 + s) * DD + tid] + b2v;
  }
  __syncthreads();

  // prefetch chunks 0,1 into ring (hidden under the gelu phase)
#pragma unroll
  for (int c = 0; c < 2; ++c)
#pragma unroll
    for (int j = 0; j < 2; ++j)
      async16(PW2X + (size_t)c * 16384 + (size_t)(j * 512 + tid) * 16,
              &sW[c * 16384 + (j * 512 + wv * 64) * 16]);

  // ---- LN1 scalars: 4 (n,w) pairs per lane (w = s*16 + lr) ----
  float al[4], bl[4];
  {
    float sqn = Sq[n], ssqn = SSq[n];
#pragma unroll
    for (int s = 0; s < 4; ++s) {
      int w = s * 16 + lr;
      float mu = (sqn + Sc[w]) * (1.0f / 1024.0f);
      float rs = rsqrtf((ssqn + SSc[w]) * (1.0f / 1024.0f) - mu * mu + 1e-5f);
      al[s] = rs; bl[s] = -rs * mu;
    }
  }

  // ---- gelu fragments -> i8 MFMA B-operand layout, 4 sets ----
  i32v4 af[4][8];
  const float* sArow = &sA[wv][0];
#pragma unroll
  for (int t8 = 0; t8 < 8; ++t8) {
    ushort8 ua[4], ub[4];
#pragma unroll
    for (int s = 0; s < 4; ++s) {
      const unsigned short* pbs = PBw + (size_t)s * 8192 + (size_t)(t8 * 64 + l) * 16;
      ua[s] = *(const ushort8*)(pbs);
      ub[s] = *(const ushort8*)(pbs + 8);
    }
    int kb = t8 * 64 + g * 16;
    unsigned dw[4][4];
#pragma unroll
    for (int j = 0; j < 4; ++j) {
      f32x4 av = *(const f32x4*)&sArow[kb + j * 4];
      f32x4 gv = *(const f32x4*)(Gv + kb + j * 4);
      f32x4 cv = *(const f32x4*)(Cc + kb + j * 4);
      float h[4][4];
#pragma unroll
      for (int i2 = 0; i2 < 4; ++i2) {
        int e = j * 4 + i2;
#pragma unroll
        for (int s = 0; s < 4; ++s) {
          float bw = bf2f(e < 8 ? ua[s][e & 7] : ub[s][e & 7]);
          float base = fmaf(bl[s], gv[i2], cv[i2]);
          h[s][i2] = gelu31(fmaf(al[s], av[i2] + bw, base));
        }
      }
#pragma unroll
      for (int s = 0; s < 4; ++s)
        dw[s][j] = quad_i8(h[s][0], h[s][1], h[s][2], h[s][3]);
    }
#pragma unroll
    for (int s = 0; s < 4; ++s) {
      i32v4 v = {(int)dw[s][0], (int)dw[s][1], (int)dw[s][2], (int)dw[s][3]};
      af[s][t8] = v;
    }
  }

  float S2[4] = {0.f, 0.f, 0.f, 0.f}, S5[4] = {0.f, 0.f, 0.f, 0.f};
  int m6[4] = {0, 0, 0, 0};
  int v1i[4] = {0, 0, 0, 0}, v3i[4] = {0, 0, 0, 0}, v4i[4] = {0, 0, 0, 0};

  const float* sQBrow = &sQB[wv][0];

#pragma unroll 1
  for (int cc = 0; cc < NCHUNK; ++cc) {
    // counted waits: chunk cc landed; cc+1's 2 loads stay in flight.
    if (cc < NCHUNK - 1) asm volatile("s_waitcnt vmcnt(2)" ::: "memory");
    else                 asm volatile("s_waitcnt vmcnt(0)" ::: "memory");
    asm volatile("s_waitcnt lgkmcnt(0)" ::: "memory");
    __builtin_amdgcn_s_barrier();
    if (cc + 2 < NCHUNK) {             // prefetch depth 2 into ring slot
      const signed char* src = PW2X + (size_t)(cc + 2) * 16384;
      signed char* dst = &sW[((cc + 2) % 3) * 16384];
#pragma unroll
      for (int j = 0; j < 2; ++j)
        async16(src + (size_t)(j * 512 + tid) * 16, dst + (j * 512 + wv * 64) * 16);
    }
    const signed char* wbuf = &sW[(cc % 3) * 16384];

    if (cc < 16) {
      i32v4 acc[4][2] = {{{0,0,0,0},{0,0,0,0}},{{0,0,0,0},{0,0,0,0}},
                         {{0,0,0,0},{0,0,0,0}},{{0,0,0,0},{0,0,0,0}}};
      __builtin_amdgcn_s_setprio(1);
#pragma unroll
      for (int t8 = 0; t8 < 8; ++t8) {
        i32v4 bf0 = *(const i32v4*)(wbuf + (size_t)(t8 * 64 + l) * 16);
        i32v4 bf1 = *(const i32v4*)(wbuf + 8192 + (size_t)(t8 * 64 + l) * 16);
#pragma unroll
        for (int s = 0; s < 4; ++s) {
          acc[s][0] = __builtin_amdgcn_mfma_i32_16x16x64_i8(bf0, af[s][t8], acc[s][0], 0, 0, 0);
          acc[s][1] = __builtin_amdgcn_mfma_i32_16x16x64_i8(bf1, af[s][t8], acc[s][1], 0, 0, 0);
        }
      }
      __builtin_amdgcn_s_setprio(0);
#pragma unroll
      for (int ct = 0; ct < 2; ++ct) {
        int cb = cc * 32 + ct * 16 + g * 4;
        f32x4 qb4 = *(const f32x4*)&sQBrow[cb];
        f32x4 gg4 = *(const f32x4*)&sGG[cb];
        f32x4 sc4 = *(const f32x4*)&sSC[cb];
#pragma unroll
        for (int s = 0; s < 4; ++s) {
#pragma unroll
          for (int r = 0; r < 4; ++r) {
            float y = fmaf((float)acc[s][ct][r], sc4[r], qb4[r]);
            float y2 = y * y;
            S2[s] += y2; S5[s] = fmaf(y2, gg4[r], S5[s]);
          }
        }
      }
    } else if (cc == 16) {
      // M6 cols 512..543: set0 x bf0, set1 x bf1 -> diagonals
      i32v4 a0 = {0,0,0,0}, a1 = {0,0,0,0};
      __builtin_amdgcn_s_setprio(1);
#pragma unroll
      for (int t8 = 0; t8 < 8; ++t8) {
        i32v4 bf0 = *(const i32v4*)(wbuf + (size_t)(t8 * 64 + l) * 16);
        i32v4 bf1 = *(const i32v4*)(wbuf + 8192 + (size_t)(t8 * 64 + l) * 16);
        a0 = __builtin_amdgcn_mfma_i32_16x16x64_i8(bf0, af[0][t8], a0, 0, 0, 0);
        a1 = __builtin_amdgcn_mfma_i32_16x16x64_i8(bf1, af[1][t8], a1, 0, 0, 0);
      }
      __builtin_amdgcn_s_setprio(0);
      int src = lr + ((lr >> 2) << 4);
      m6[0] = __shfl(sel4i(a0, lr & 3), src, 64);
      m6[1] = __shfl(sel4i(a1, lr & 3), src, 64);
    } else if (cc == 17) {
      // M6 cols 544..575: set2 x bf0, set3 x bf1
      i32v4 a0 = {0,0,0,0}, a1 = {0,0,0,0};
      __builtin_amdgcn_s_setprio(1);
#pragma unroll
      for (int t8 = 0; t8 < 8; ++t8) {
        i32v4 bf0 = *(const i32v4*)(wbuf + (size_t)(t8 * 64 + l) * 16);
        i32v4 bf1 = *(const i32v4*)(wbuf + 8192 + (size_t)(t8 * 64 + l) * 16);
        a0 = __builtin_amdgcn_mfma_i32_16x16x64_i8(bf0, af[2][t8], a0, 0, 0, 0);
        a1 = __builtin_amdgcn_mfma_i32_16x16x64_i8(bf1, af[3][t8], a1, 0, 0, 0);
      }
      __builtin_amdgcn_s_setprio(0);
      int src = lr + ((lr >> 2) << 4);
      m6[2] = __shfl(sel4i(a0, lr & 3), src, 64);
      m6[3] = __shfl(sel4i(a1, lr & 3), src, 64);
    } else {
      // v-chunk: v1,v3,v4 at rows 0,1,2 of first col-tile
      i32v4 av_[4] = {{0,0,0,0},{0,0,0,0},{0,0,0,0},{0,0,0,0}};
      __builtin_amdgcn_s_setprio(1);
#pragma unroll
      for (int t8 = 0; t8 < 8; ++t8) {
        i32v4 bf0 = *(const i32v4*)(wbuf + (size_t)(t8 * 64 + l) * 16);
#pragma unroll
        for (int s = 0; s < 4; ++s)
          av_[s] = __builtin_amdgcn_mfma_i32_16x16x64_i8(bf0, af[s][t8], av_[s], 0, 0, 0);
      }
      __builtin_amdgcn_s_setprio(0);
#pragma unroll
      for (int s = 0; s < 4; ++s) {
        v1i[s] = __shfl(av_[s][0], lr, 64);
        v3i[s] = __shfl(av_[s][1], lr, 64);
        v4i[s] = __shfl(av_[s][2], lr, 64);
      }
    }
  }

#pragma unroll
  for (int s = 0; s < 4; ++s) {
    S2[s] += __shfl_xor(S2[s], 16, 64); S2[s] += __shfl_xor(S2[s], 32, 64);
    S5[s] += __shfl_xor(S5[s], 16, 64); S5[s] += __shfl_xor(S5[s], 32, 64);
  }

  if (g == 0) {
    float sg2v = scal[0], sgbv = scal[1], sb2v = scal[2];
    float qbs = qst[n * 4 + 0], qggs = qst[n * 4 + 1], qgbs = qst[n * 4 + 2];
#pragma unroll
    for (int s = 0; s < 4; ++s) {
      int w = s * 16 + lr;
      float S1 = (float)v1i[s] * sSC[576] + qbs;
      float S3 = (float)v3i[s] * sSC[577] + qggs;
      float S4 = (float)v4i[s] * sSC[578] + qgbs;
      float S6 = (float)m6[s] * sSC[512 + w] + QC[(size_t)n * NWC + w] + c3v[w];
      float mu2 = S1 * (1.0f / 512.0f);
      float var2 = S2[s] * (1.0f / 512.0f) - mu2 * mu2;
      float rs2 = rsqrtf(var2 + 1e-5f);
      float n2 = rs2 * rs2 * (S5[s] - 2.f * mu2 * S3 + mu2 * mu2 * sg2v)
               + 2.f * rs2 * (S4 - mu2 * sgbv) + sb2v;
      float num = rs2 * (S6 - mu2 * c1v[w]) + c2v[w];
      out[(size_t)n * NWC + w] = 16.0f * num / fmaxf(sqrtf(fmaxf(n2, 0.f)), 1e-12f);
    }
  }
}

// ---------------- launch ----------------

extern "C" void kernel_launch(void* const* d_in, const int* in_sizes, int n_in,
                              void* d_out, int out_size, void* d_ws, size_t ws_size,
                              hipStream_t stream) {
  const float* q    = (const float*)d_in[0];
  const float* cm   = (const float*)d_in[1];
  const float* ln1w = (const float*)d_in[2];
  const float* ln1b = (const float*)d_in[3];
  const float* w1   = (const float*)d_in[4];
  const float* b1   = (const float*)d_in[5];
  const float* w2   = (const float*)d_in[6];
  const float* b2   = (const float*)d_in[7];
  const float* ln2w = (const float*)d_in[8];
  const float* ln2b = (const float*)d_in[9];
  float* out = (float*)d_out;

  char* p = (char*)d_ws;
  auto alloc = [&](size_t bytes) { char* r = p; p += (bytes + 255) & ~(size_t)255; return r; };
  float* A     = (float*)alloc((size_t)NQ * DD * 4);
  unsigned short* Bwb = (unsigned short*)alloc((size_t)NWC * DD * 2);
  float* G     = (float*)alloc(DD * 4);
  float* C     = (float*)alloc(DD * 4);
  float* Gp    = (float*)alloc((size_t)16 * DD * 4);
  float* Cp    = (float*)alloc((size_t)16 * DD * 4);
  float* Sq    = (float*)alloc(NQ * 4);
  float* SSq   = (float*)alloc(NQ * 4);
  float* Sc    = (float*)alloc(NWC * 4);
  float* SSc   = (float*)alloc(NWC * 4);
  float* cmhg  = (float*)alloc((size_t)NWC * DD * 4);
  float* c1    = (float*)alloc(NWC * 4);
  float* c2    = (float*)alloc(NWC * 4);
  float* c3    = (float*)alloc(NWC * 4);
  float* gg    = (float*)alloc(DD * 4);
  float* scal  = (float*)alloc(256);
  float* qst   = (float*)alloc((size_t)NQ * 4 * 4);
  float* QC    = (float*)alloc((size_t)NQ * NWC * 4);
  float* M6buf = (float*)alloc((size_t)DD * NWC * 4);
  float* Vbuf  = (float*)alloc((size_t)DD * 4 * 4);
  float* Scl   = (float*)alloc(608 * 4);
  unsigned short* PW1T = (unsigned short*)alloc((size_t)DD * DD * 2);
  unsigned short* PW1B = (unsigned short*)alloc((size_t)DD * DD * 2);
  unsigned short* PCT  = (unsigned short*)alloc((size_t)DD * NWC * 2);
  unsigned short* PBw  = (unsigned short*)alloc((size_t)NWC * DD * 2);
  signed char* PW2X    = (signed char*)alloc((size_t)38 * 8192);

  k_prep<<<401, 256, 0, stream>>>(q, cm, ln1w, ln1b, w1, w2, ln2w, ln2b, b2,
                                  Sq, SSq, qst, Sc, SSc, cmhg, c1, c2, c3,
                                  Gp, Cp, Vbuf, gg, scal);
  k_pack1<<<136, 512, 0, stream>>>(w1, ln1w, cmhg, PW1T, PW1B, PCT);
  k_gemms<<<304, 256, 0, stream>>>(q, cm, w2, PW1T, PW1B, PCT, A, Bwb, QC, M6buf);
  k_pack2<<<43, 512, 0, stream>>>(w2, M6buf, Vbuf, Bwb, Gp, Cp, b1, PW2X, PBw, G, C, Scl);
  k_main<<<256, 512, 0, stream>>>(A, PBw, G, C, q, b2, gg, qst, QC, c1, c2, c3,
                                  Sq, SSq, Sc, SSc, scal, PW2X, Scl, out);
}

// Round 11
// 117.684 us; speedup vs baseline: 1.2387x; 1.2387x over previous
//
#include <hip/hip_runtime.h>
#include <cstdint>
#include <cstddef>

// ---------------------------------------------------------------------------
// HierarchicalQueryMatcher, N=2048, W=64, D=512.
//   LN1(x)@w1+b1 = rs*(A[n,:]+B[w,:]) - rs*mu*G + C
//   h2 = gelu(h) @ w2 ; y = h2 + q[n] + b2
//   out = 16 * dot(LN2(y), cmhat)/max(||LN2(y)||,eps)
// Linear-in-h2 sums folded into extra GEMM cols (M6 = w2@cmhg^T, v1,v3,v4);
// quadratic sums (S2,S5) streamed in the MFMA epilogue. h2-GEMM in INT8.
// Round 11 = r6 anchor (118us) + __launch_bounds__(512,4): force unified
// regs <= 128/wave so TWO 8-wave blocks fit per CU (LDS 74KB x2 <= 160KB).
// Occupancy 2 -> 4 waves/SIMD; the three half-idle pipes (VALU/LDS/MFMA)
// co-schedule across 2x the waves (m114). quad_i8 + fmed3 micro-opts kept.
// ---------------------------------------------------------------------------

#define NQ 2048
#define NWC 64
#define DD 512
#define NCHUNK 19
#define SA_CONST (4.0f / 127.0f)
#define MAGICF 12582912.0f

typedef __attribute__((ext_vector_type(8))) short short8;
typedef __attribute__((ext_vector_type(8))) unsigned short ushort8;
typedef __attribute__((ext_vector_type(4))) float f32x4;
typedef __attribute__((ext_vector_type(4))) int i32v4;
typedef __attribute__((ext_vector_type(4))) unsigned u32x4;

__device__ __forceinline__ unsigned short f2bf(float f) {
  unsigned u = __float_as_uint(f);
  u += 0x7fffu + ((u >> 16) & 1u);
  return (unsigned short)(u >> 16);
}

__device__ __forceinline__ unsigned cvtpk2(float lo, float hi) {
  unsigned r;
  asm("v_cvt_pk_bf16_f32 %0, %1, %2" : "=v"(r) : "v"(lo), "v"(hi));
  return r;
}

__device__ __forceinline__ float bf2f(unsigned short u) {
  return __uint_as_float(((unsigned)u) << 16);
}

// gelu(h)*31.75, clamped to [-127,127] via med3.
__device__ __forceinline__ float gelu31(float h) {
  float h2 = h * h;
  float zn = h * fmaf(h2, -0.10295890518f, -2.30221607f); // -z*log2(e)
  float t = exp2f(zn);
  float r = __builtin_amdgcn_rcpf(1.0f + t);
  float gv = (h * 31.75f) * r;
  return __builtin_amdgcn_fmed3f(gv, -127.0f, 127.0f);
}

// 4 clamped floats -> packed i8 dword via magic-round + byte_perm (7 ops).
__device__ __forceinline__ unsigned quad_i8(float a, float b, float c, float d) {
  unsigned u0 = __float_as_uint(a + MAGICF);
  unsigned u1 = __float_as_uint(b + MAGICF);
  unsigned u2 = __float_as_uint(c + MAGICF);
  unsigned u3 = __float_as_uint(d + MAGICF);
  unsigned s1 = __byte_perm(u0, u1, 0x0040);
  unsigned s2 = __byte_perm(u2, u3, 0x0040);
  return __byte_perm(s1, s2, 0x5410);
}

__device__ __forceinline__ float wred(float v) {
#pragma unroll
  for (int m = 1; m < 64; m <<= 1) v += __shfl_xor(v, m, 64);
  return v;
}

__device__ __forceinline__ int sel4i(i32v4 v, int r) {
  int x = (r & 1) ? v[1] : v[0];
  int y = (r & 1) ? v[3] : v[2];
  return (r & 2) ? y : x;
}

// ---------------- k_prep: all O(N*D) precompute in one launch ----------------
__global__ __launch_bounds__(256) void k_prep(
    const float* __restrict__ q, const float* __restrict__ cm,
    const float* __restrict__ g1, const float* __restrict__ be1,
    const float* __restrict__ w1, const float* __restrict__ w2,
    const float* __restrict__ g2, const float* __restrict__ be2,
    const float* __restrict__ b2,
    float* __restrict__ Sq, float* __restrict__ SSq, float* __restrict__ qst,
    float* __restrict__ Sc, float* __restrict__ SSc, float* __restrict__ cmhg,
    float* __restrict__ c1, float* __restrict__ c2, float* __restrict__ c3,
    float* __restrict__ Gp, float* __restrict__ Cp, float* __restrict__ V,
    float* __restrict__ gg, float* __restrict__ scal) {
  const int b = blockIdx.x, tid = threadIdx.x;
  const int wv = tid >> 6, l = tid & 63;
  __shared__ float shr[3][4];
  __shared__ float s_inv;

  if (b < 256) {
    f32x4 b20 = *(const f32x4*)(b2 + l * 8);
    f32x4 b21 = *(const f32x4*)(b2 + l * 8 + 4);
    f32x4 g20 = *(const f32x4*)(g2 + l * 8);
    f32x4 g21 = *(const f32x4*)(g2 + l * 8 + 4);
    f32x4 e20 = *(const f32x4*)(be2 + l * 8);
    f32x4 e21 = *(const f32x4*)(be2 + l * 8 + 4);
#pragma unroll
    for (int rr = 0; rr < 2; ++rr) {
      int r = b * 8 + wv * 2 + rr;
      const float* row = q + (size_t)r * DD;
      f32x4 q0 = *(const f32x4*)(row + l * 8);
      f32x4 q1 = *(const f32x4*)(row + l * 8 + 4);
      float s0 = 0, s1 = 0, s2 = 0, s3 = 0, s4 = 0;
#pragma unroll
      for (int i = 0; i < 4; ++i) {
        float v = q0[i]; s0 += v; s1 = fmaf(v, v, s1);
        float qb = v + b20[i], g = g20[i];
        s2 += qb; s3 = fmaf(qb, g * g, s3); s4 = fmaf(qb, g * e20[i], s4);
        v = q1[i]; s0 += v; s1 = fmaf(v, v, s1);
        qb = v + b21[i]; g = g21[i];
        s2 += qb; s3 = fmaf(qb, g * g, s3); s4 = fmaf(qb, g * e21[i], s4);
      }
      s0 = wred(s0); s1 = wred(s1); s2 = wred(s2); s3 = wred(s3); s4 = wred(s4);
      if (l == 0) {
        Sq[r] = s0; SSq[r] = s1;
        qst[r * 4 + 0] = s2; qst[r * 4 + 1] = s3; qst[r * 4 + 2] = s4;
      }
    }
  } else if (b < 320) {
    int w = b - 256;
    const float* row = cm + (size_t)w * DD;
    float sm = 0.f, ss = 0.f;
    for (int c = tid; c < DD; c += 256) { float v = row[c]; sm += v; ss = fmaf(v, v, ss); }
    sm = wred(sm); ss = wred(ss);
    if (l == 0) { shr[0][wv] = sm; shr[1][wv] = ss; }
    __syncthreads();
    if (tid == 0) {
      float smt = shr[0][0] + shr[0][1] + shr[0][2] + shr[0][3];
      float sst = shr[1][0] + shr[1][1] + shr[1][2] + shr[1][3];
      Sc[w] = smt; SSc[w] = sst;
      s_inv = 1.0f / fmaxf(sqrtf(sst), 1e-12f);
    }
    __syncthreads();
    float inv = s_inv;
    float a = 0.f, bs = 0.f, d = 0.f;
    for (int c = tid; c < DD; c += 256) {
      float ch = row[c] * inv;
      float gv = g2[c];
      float gch = gv * ch;
      cmhg[(size_t)w * DD + c] = gch;
      a += gch;
      bs = fmaf(be2[c], ch, bs);
      d = fmaf(b2[c], gch, d);
    }
    a = wred(a); bs = wred(bs); d = wred(d);
    __syncthreads();
    if (l == 0) { shr[0][wv] = a; shr[1][wv] = bs; shr[2][wv] = d; }
    __syncthreads();
    if (tid == 0) {
      c1[w] = shr[0][0] + shr[0][1] + shr[0][2] + shr[0][3];
      c2[w] = shr[1][0] + shr[1][1] + shr[1][2] + shr[1][3];
      c3[w] = shr[2][0] + shr[2][1] + shr[2][2] + shr[2][3];
    }
  } else if (b < 336) {
    int bk = b - 320, k0 = bk * 64;
#pragma unroll
    for (int jh = 0; jh < 2; ++jh) {
      int j = tid + jh * 256;
      float g = 0.f, c = 0.f;
#pragma unroll 4
      for (int k = 0; k < 64; ++k) {
        float wv4 = w1[(size_t)(k0 + k) * DD + j];
        g = fmaf(g1[k0 + k], wv4, g);
        c = fmaf(be1[k0 + k], wv4, c);
      }
      Gp[(size_t)bk * DD + j] = g;
      Cp[(size_t)bk * DD + j] = c;
    }
  } else if (b < 400) {
    int bb = b - 336;
    f32x4 g20 = *(const f32x4*)(g2 + l * 8);
    f32x4 g21 = *(const f32x4*)(g2 + l * 8 + 4);
    f32x4 e20 = *(const f32x4*)(be2 + l * 8);
    f32x4 e21 = *(const f32x4*)(be2 + l * 8 + 4);
#pragma unroll
    for (int rr = 0; rr < 2; ++rr) {
      int k = bb * 8 + wv * 2 + rr;
      const float* row = w2 + (size_t)k * DD;
      f32x4 w0 = *(const f32x4*)(row + l * 8);
      f32x4 w1v = *(const f32x4*)(row + l * 8 + 4);
      float s1 = 0, s3 = 0, s4 = 0;
#pragma unroll
      for (int i = 0; i < 4; ++i) {
        float w = w0[i], g = g20[i];
        s1 += w; s3 = fmaf(w, g * g, s3); s4 = fmaf(w, g * e20[i], s4);
        w = w1v[i]; g = g21[i];
        s1 += w; s3 = fmaf(w, g * g, s3); s4 = fmaf(w, g * e21[i], s4);
      }
      s1 = wred(s1); s3 = wred(s3); s4 = wred(s4);
      if (l == 0) {
        V[k * 4 + 0] = s1; V[k * 4 + 1] = s3; V[k * 4 + 2] = s4; V[k * 4 + 3] = 0.f;
      }
    }
  } else {
    float a0 = 0, a1 = 0, a2 = 0;
    for (int c = tid; c < DD; c += 256) {
      float g = g2[c], be = be2[c];
      gg[c] = g * g;
      a0 = fmaf(g, g, a0); a1 = fmaf(g, be, a1); a2 = fmaf(be, be, a2);
    }
    a0 = wred(a0); a1 = wred(a1); a2 = wred(a2);
    if (l == 0) { shr[0][wv] = a0; shr[1][wv] = a1; shr[2][wv] = a2; }
    __syncthreads();
    if (tid == 0) {
      scal[0] = shr[0][0] + shr[0][1] + shr[0][2] + shr[0][3];
      scal[1] = shr[1][0] + shr[1][1] + shr[1][2] + shr[1][3];
      scal[2] = shr[2][0] + shr[2][1] + shr[2][2] + shr[2][3];
    }
  }
}

// ---------------- k_pack1: PW1T + PW1B + PCT (bf16 GEMM operands) -------------
__global__ __launch_bounds__(512) void k_pack1(
    const float* __restrict__ w1, const float* __restrict__ ln1w,
    const float* __restrict__ cmhg,
    unsigned short* __restrict__ PW1T, unsigned short* __restrict__ PW1B,
    unsigned short* __restrict__ PCT) {
  int b = blockIdx.x;
  if (b < 128) {
    int roff = (b < 64) ? 0 : 512;
    unsigned short* out = (b < 64) ? PW1T : PW1B;
    int tid = (b & 63) * 512 + threadIdx.x;
    int l = tid & 63, t = (tid >> 6) & 15, ct = tid >> 10, g = l >> 4;
    int col = (ct << 4) + (l & 15);
    ushort8 o;
#pragma unroll
    for (int i = 0; i < 8; ++i) {
      int k = t * 32 + g * 8 + i;
      o[i] = f2bf(w1[(size_t)(roff + k) * DD + col] * ln1w[roff + k]);
    }
    *(ushort8*)(out + (size_t)tid * 8) = o;
  } else {
    int tid = (b - 128) * 512 + threadIdx.x;
    int l = tid & 63, t = (tid >> 6) & 15, g = l >> 4;
    int col = ((tid >> 10) << 4) + (l & 15);
    ushort8 o;
#pragma unroll
    for (int i = 0; i < 8; ++i) {
      int k = t * 32 + g * 8 + i;
      o[i] = f2bf(cmhg[(size_t)col * DD + k]);
    }
    *(ushort8*)(PCT + (size_t)tid * 8) = o;
  }
}

// ---------------- k_gemms: 4 bf16 GEMM jobs in one dispatch -------------------
__global__ __launch_bounds__(256) void k_gemms(
    const float* __restrict__ q, const float* __restrict__ cm,
    const float* __restrict__ w2,
    const unsigned short* __restrict__ PW1T, const unsigned short* __restrict__ PW1B,
    const unsigned short* __restrict__ PCT,
    float* __restrict__ A, unsigned short* __restrict__ Bwb,
    float* __restrict__ QC, float* __restrict__ M6) {
  int b = blockIdx.x;
  const float* X; const unsigned short* PW; void* Out;
  int bx, by, ostride, obf;
  if (b < 256)      { X = q;  PW = PW1T; Out = A;    bx = b & 7;   by = b >> 3;  ostride = DD;  obf = 0; }
  else if (b < 264) { X = cm; PW = PW1B; Out = Bwb;  bx = b - 256; by = 0;       ostride = DD;  obf = 1; }
  else if (b < 296) { X = q;  PW = PCT;  Out = QC;   bx = 0;       by = b - 264; ostride = NWC; obf = 0; }
  else              { X = w2; PW = PCT;  Out = M6;   bx = 0;       by = b - 296; ostride = NWC; obf = 0; }

  int l = threadIdx.x & 63;
  int wv = threadIdx.x >> 6;
  int lr = l & 15, g = l >> 4;
  int r0 = by * 64 + wv * 16;
  int cb0 = bx * 4;
  f32x4 acc[4] = {{0,0,0,0},{0,0,0,0},{0,0,0,0},{0,0,0,0}};
  const float* xrow = X + (size_t)(r0 + lr) * DD;
#pragma unroll
  for (int t = 0; t < 16; ++t) {
    int kb = t * 32 + g * 8;
    f32x4 x0 = *(const f32x4*)(xrow + kb);
    f32x4 x1 = *(const f32x4*)(xrow + kb + 4);
    union { short8 s; unsigned u[4]; } af;
    af.u[0] = cvtpk2(x0[0], x0[1]);
    af.u[1] = cvtpk2(x0[2], x0[3]);
    af.u[2] = cvtpk2(x1[0], x1[1]);
    af.u[3] = cvtpk2(x1[2], x1[3]);
#pragma unroll
    for (int c = 0; c < 4; ++c) {
      short8 bf = *(const short8*)(PW + (size_t)(((cb0 + c) * 16 + t) * 64 + l) * 8);
      acc[c] = __builtin_amdgcn_mfma_f32_16x16x32_bf16(af.s, bf, acc[c], 0, 0, 0);
    }
  }
#pragma unroll
  for (int c = 0; c < 4; ++c)
#pragma unroll
    for (int r = 0; r < 4; ++r) {
      size_t idx = (size_t)(r0 + g * 4 + r) * ostride + (cb0 + c) * 16 + lr;
      float v = acc[c][r];
      if (obf) ((unsigned short*)Out)[idx] = f2bf(v);
      else     ((float*)Out)[idx] = v;
    }
}

// ---------------- k_pack2: i8 W2X + scales + PBw + G/C ------------------------
__global__ __launch_bounds__(512) void k_pack2(
    const float* __restrict__ w2, const float* __restrict__ M6,
    const float* __restrict__ V, const unsigned short* __restrict__ Bwb,
    const float* __restrict__ Gp, const float* __restrict__ Cp,
    const float* __restrict__ b1,
    signed char* __restrict__ PW2X, unsigned short* __restrict__ PBw,
    float* __restrict__ G, float* __restrict__ C, float* __restrict__ Scales) {
  int b = blockIdx.x, tx = threadIdx.x;
  __shared__ float red[16][33];
  __shared__ float sinv[16];
  if (b < 38) {
    int ct = b;
    int t8 = tx >> 6, l = tx & 63, g4 = l >> 4, lc = l & 15;
    int col = ct * 16 + lc;
    float v[16]; float lmax = 0.f;
#pragma unroll
    for (int i = 0; i < 16; ++i) {
      int k = t8 * 64 + g4 * 16 + i;
      float x;
      if (col < 512)      x = w2[(size_t)k * DD + col];
      else if (col < 576) x = M6[(size_t)k * 64 + (col - 512)];
      else { int cv = col - 576; x = (cv < 3) ? V[k * 4 + cv] : 0.f; }
      v[i] = x; lmax = fmaxf(lmax, fabsf(x));
    }
    red[lc][t8 * 4 + g4] = lmax;
    __syncthreads();
    if (tx < 16) {
      float m = 0.f;
#pragma unroll
      for (int j = 0; j < 32; ++j) m = fmaxf(m, red[tx][j]);
      float sc = fmaxf(m, 1e-20f) * (1.0f / 127.0f);
      Scales[ct * 16 + tx] = sc;
      sinv[tx] = 1.0f / sc;
    }
    __syncthreads();
    float inv = sinv[lc];
    u32x4 d;
#pragma unroll
    for (int j = 0; j < 4; ++j) {
      unsigned u = 0;
#pragma unroll
      for (int e = 0; e < 4; ++e) {
        float qv = v[j * 4 + e] * inv;
        qv = fminf(fmaxf(qv, -127.f), 127.f);
        int iq = (int)rintf(qv);
        u |= ((unsigned)(iq & 255)) << (8 * e);
      }
      d[j] = u;
    }
    *(u32x4*)(PW2X + (size_t)ct * 8192 + (size_t)(t8 * 64 + l) * 16) = d;
  } else if (b < 42) {
    int slot = (b - 38) * 512 + tx;  // 2048 slots
    int wt = slot >> 9, r = slot & 511, t8 = r >> 6, l = r & 63;
    int w = wt * 16 + (l & 15);
    int kb = t8 * 64 + (l >> 4) * 16;
    ushort8 o0, o1;
#pragma unroll
    for (int i = 0; i < 8; ++i) {
      o0[i] = Bwb[(size_t)w * DD + kb + i];
      o1[i] = Bwb[(size_t)w * DD + kb + 8 + i];
    }
    *(ushort8*)(PBw + (size_t)slot * 16) = o0;
    *(ushort8*)(PBw + (size_t)slot * 16 + 8) = o1;
  } else {
    int c = tx;
    float g = 0.f, cc2 = 0.f;
#pragma unroll
    for (int p = 0; p < 16; ++p) { g += Gp[p * DD + c]; cc2 += Cp[p * DD + c]; }
    G[c] = g; C[c] = cc2 + b1[c];
  }
}

// ---------------- fused main kernel: i8 GEMM, counted-vmcnt 3-ring ------------

__device__ __forceinline__ void async16(const void* g, void* lds) {
  __builtin_amdgcn_global_load_lds(
      (const __attribute__((address_space(1))) void*)(uintptr_t)g,
      (__attribute__((address_space(3))) void*)(unsigned int)(uintptr_t)lds,
      16, 0, 0);
}

__global__ __launch_bounds__(512, 4) void k_main(
    const float* __restrict__ Afull, const unsigned short* __restrict__ PBw,
    const float* __restrict__ G, const float* __restrict__ Cc,
    const float* __restrict__ q, const float* __restrict__ b2,
    const float* __restrict__ gg, const float* __restrict__ qst,
    const float* __restrict__ QC, const float* __restrict__ c1v,
    const float* __restrict__ c2v, const float* __restrict__ c3v,
    const float* __restrict__ Sq, const float* __restrict__ SSq,
    const float* __restrict__ Sc, const float* __restrict__ SSc,
    const float* __restrict__ scal, const signed char* __restrict__ PW2X,
    const float* __restrict__ Scales, float* __restrict__ out) {

  __shared__ __align__(16) float sG[DD], sC[DD], sGG[DD], sSC[608];
  __shared__ __align__(16) float sA[4][DD], sQB[4][DD];
  __shared__ __align__(16) signed char sW[3 * 16384];   // 3x16KB i8 chunk ring

  const int tid = threadIdx.x;
  const int wv = tid >> 6, l = tid & 63;
  const int g = l >> 4, lr = l & 15;
  const int n0 = blockIdx.x * 4;
  const int sub = wv >> 1;             // which n of the 4
  const int n = n0 + sub;
  const int whalf = wv & 1;
  const int w0 = whalf * 32 + lr;
  const int w1p = w0 + 16;

  // ---- stage block-wide LDS state ----
  sG[tid] = G[tid]; sC[tid] = Cc[tid]; sGG[tid] = gg[tid];
  for (int i = tid; i < 608; i += 512) sSC[i] = Scales[i] * SA_CONST;
#pragma unroll
  for (int s = 0; s < 4; ++s) {
    sA[s][tid]  = Afull[(size_t)(n0 + s) * DD + tid];
    sQB[s][tid] = q[(size_t)(n0 + s) * DD + tid] + b2[tid];
  }
  __syncthreads();

  // prefetch chunks 0,1 (hidden under the gelu phase). 2 loads/thread/chunk.
#pragma unroll
  for (int c = 0; c < 2; ++c)
#pragma unroll
    for (int j = 0; j < 2; ++j)
      async16(PW2X + (size_t)c * 16384 + (size_t)(j * 512 + tid) * 16,
              &sW[c * 16384 + (j * 512 + wv * 64) * 16]);

  // ---- LN1 scalars for this lane's two (n,w) pairs ----
  float sqn = Sq[n], ssqn = SSq[n];
  float mu0 = (sqn + Sc[w0]) * (1.0f / 1024.0f);
  float rs0 = rsqrtf((ssqn + SSc[w0]) * (1.0f / 1024.0f) - mu0 * mu0 + 1e-5f);
  float mu1 = (sqn + Sc[w1p]) * (1.0f / 1024.0f);
  float rs1 = rsqrtf((ssqn + SSc[w1p]) * (1.0f / 1024.0f) - mu1 * mu1 + 1e-5f);
  float al0 = rs0, bl0 = -rs0 * mu0;
  float al1 = rs1, bl1 = -rs1 * mu1;

  // ---- gelu fragments -> i8 MFMA B-operand layout (k = t8*64 + g*16 + i) ----
  i32v4 af0[8], af1[8];
  const unsigned short* pb0 = PBw + (size_t)(whalf * 2) * 8192;
  const unsigned short* pb1 = PBw + (size_t)(whalf * 2 + 1) * 8192;
#pragma unroll
  for (int t8 = 0; t8 < 8; ++t8) {
    int kb = t8 * 64 + g * 16;
    ushort8 u0a = *(const ushort8*)(pb0 + (size_t)(t8 * 64 + l) * 16);
    ushort8 u0b = *(const ushort8*)(pb0 + (size_t)(t8 * 64 + l) * 16 + 8);
    ushort8 u1a = *(const ushort8*)(pb1 + (size_t)(t8 * 64 + l) * 16);
    ushort8 u1b = *(const ushort8*)(pb1 + (size_t)(t8 * 64 + l) * 16 + 8);
    unsigned dw0[4], dw1[4];
#pragma unroll
    for (int j = 0; j < 4; ++j) {
      f32x4 av = *(const f32x4*)&sA[sub][kb + j * 4];
      f32x4 gv = *(const f32x4*)&sG[kb + j * 4];
      f32x4 cv = *(const f32x4*)&sC[kb + j * 4];
      float hA[4], hB[4];
#pragma unroll
      for (int i2 = 0; i2 < 4; ++i2) {
        int e = j * 4 + i2;
        float bw0 = bf2f(e < 8 ? u0a[e & 7] : u0b[e & 7]);
        float bw1 = bf2f(e < 8 ? u1a[e & 7] : u1b[e & 7]);
        float base0 = fmaf(bl0, gv[i2], cv[i2]);
        float base1 = fmaf(bl1, gv[i2], cv[i2]);
        hA[i2] = gelu31(fmaf(al0, av[i2] + bw0, base0));
        hB[i2] = gelu31(fmaf(al1, av[i2] + bw1, base1));
      }
      dw0[j] = quad_i8(hA[0], hA[1], hA[2], hA[3]);
      dw1[j] = quad_i8(hB[0], hB[1], hB[2], hB[3]);
    }
    i32v4 a0v = {(int)dw0[0], (int)dw0[1], (int)dw0[2], (int)dw0[3]};
    i32v4 a1v = {(int)dw1[0], (int)dw1[1], (int)dw1[2], (int)dw1[3]};
    af0[t8] = a0v; af1[t8] = a1v;
  }

  float S20 = 0.f, S50 = 0.f, S21 = 0.f, S51 = 0.f;
  int m6i0 = 0, m6i1 = 0;
  int v1i0 = 0, v3i0 = 0, v4i0 = 0;
  int v1i1 = 0, v3i1 = 0, v4i1 = 0;

#pragma unroll 1
  for (int cc = 0; cc < NCHUNK; ++cc) {
    // counted waits: chunk cc landed; cc+1's 2 loads stay in flight.
    if (cc < NCHUNK - 1) asm volatile("s_waitcnt vmcnt(2)" ::: "memory");
    else                 asm volatile("s_waitcnt vmcnt(0)" ::: "memory");
    asm volatile("s_waitcnt lgkmcnt(0)" ::: "memory");
    __builtin_amdgcn_s_barrier();
    if (cc + 2 < NCHUNK) {             // prefetch depth 2 into ring slot
      const signed char* src = PW2X + (size_t)(cc + 2) * 16384;
      signed char* dst = &sW[((cc + 2) % 3) * 16384];
#pragma unroll
      for (int j = 0; j < 2; ++j)
        async16(src + (size_t)(j * 512 + tid) * 16, dst + (j * 512 + wv * 64) * 16);
    }
    const signed char* wbuf = &sW[(cc % 3) * 16384];

    if (cc < 16) {
      i32v4 acc00 = {0,0,0,0}, acc01 = {0,0,0,0}, acc10 = {0,0,0,0}, acc11 = {0,0,0,0};
      __builtin_amdgcn_s_setprio(1);
#pragma unroll
      for (int t8 = 0; t8 < 8; ++t8) {
        i32v4 bf0 = *(const i32v4*)(wbuf + (size_t)(t8 * 64 + l) * 16);
        i32v4 bf1 = *(const i32v4*)(wbuf + 8192 + (size_t)(t8 * 64 + l) * 16);
        acc00 = __builtin_amdgcn_mfma_i32_16x16x64_i8(bf0, af0[t8], acc00, 0, 0, 0);
        acc10 = __builtin_amdgcn_mfma_i32_16x16x64_i8(bf0, af1[t8], acc10, 0, 0, 0);
        acc01 = __builtin_amdgcn_mfma_i32_16x16x64_i8(bf1, af0[t8], acc01, 0, 0, 0);
        acc11 = __builtin_amdgcn_mfma_i32_16x16x64_i8(bf1, af1[t8], acc11, 0, 0, 0);
      }
      __builtin_amdgcn_s_setprio(0);
#pragma unroll
      for (int ct = 0; ct < 2; ++ct) {
        int cb = cc * 32 + ct * 16 + g * 4;
        f32x4 qb4 = *(const f32x4*)&sQB[sub][cb];
        f32x4 gg4 = *(const f32x4*)&sGG[cb];
        f32x4 sc4 = *(const f32x4*)&sSC[cb];
        i32v4 aAv = ct ? acc01 : acc00;
        i32v4 aBv = ct ? acc11 : acc10;
#pragma unroll
        for (int r = 0; r < 4; ++r) {
          float y = fmaf((float)aAv[r], sc4[r], qb4[r]);
          float y2 = y * y;
          S20 += y2; S50 = fmaf(y2, gg4[r], S50);
          float z = fmaf((float)aBv[r], sc4[r], qb4[r]);
          float z2 = z * z;
          S21 += z2; S51 = fmaf(z2, gg4[r], S51);
        }
      }
    } else if (cc == 16 || cc == 17) {
      if (cc == 16 + whalf) {
        i32v4 acc00 = {0,0,0,0}, acc11 = {0,0,0,0};
        __builtin_amdgcn_s_setprio(1);
#pragma unroll
        for (int t8 = 0; t8 < 8; ++t8) {
          i32v4 bf0 = *(const i32v4*)(wbuf + (size_t)(t8 * 64 + l) * 16);
          i32v4 bf1 = *(const i32v4*)(wbuf + 8192 + (size_t)(t8 * 64 + l) * 16);
          acc00 = __builtin_amdgcn_mfma_i32_16x16x64_i8(bf0, af0[t8], acc00, 0, 0, 0);
          acc11 = __builtin_amdgcn_mfma_i32_16x16x64_i8(bf1, af1[t8], acc11, 0, 0, 0);
        }
        __builtin_amdgcn_s_setprio(0);
        int d0 = sel4i(acc00, lr & 3);
        int d1 = sel4i(acc11, lr & 3);
        int src = lr + ((lr >> 2) << 4);
        m6i0 = __shfl(d0, src, 64);
        m6i1 = __shfl(d1, src, 64);
      }
    } else {
      i32v4 acc00 = {0,0,0,0}, acc10 = {0,0,0,0};
      __builtin_amdgcn_s_setprio(1);
#pragma unroll
      for (int t8 = 0; t8 < 8; ++t8) {
        i32v4 bf0 = *(const i32v4*)(wbuf + (size_t)(t8 * 64 + l) * 16);
        acc00 = __builtin_amdgcn_mfma_i32_16x16x64_i8(bf0, af0[t8], acc00, 0, 0, 0);
        acc10 = __builtin_amdgcn_mfma_i32_16x16x64_i8(bf0, af1[t8], acc10, 0, 0, 0);
      }
      __builtin_amdgcn_s_setprio(0);
      v1i0 = __shfl(acc00[0], lr, 64);
      v3i0 = __shfl(acc00[1], lr, 64);
      v4i0 = __shfl(acc00[2], lr, 64);
      v1i1 = __shfl(acc10[0], lr, 64);
      v3i1 = __shfl(acc10[1], lr, 64);
      v4i1 = __shfl(acc10[2], lr, 64);
    }
  }

  S20 += __shfl_xor(S20, 16, 64); S20 += __shfl_xor(S20, 32, 64);
  S50 += __shfl_xor(S50, 16, 64); S50 += __shfl_xor(S50, 32, 64);
  S21 += __shfl_xor(S21, 16, 64); S21 += __shfl_xor(S21, 32, 64);
  S51 += __shfl_xor(S51, 16, 64); S51 += __shfl_xor(S51, 32, 64);

  if (g == 0) {
    float sg2v = scal[0], sgbv = scal[1], sb2v = scal[2];
    float qbs = qst[n * 4 + 0], qggs = qst[n * 4 + 1], qgbs = qst[n * 4 + 2];
#pragma unroll
    for (int p = 0; p < 2; ++p) {
      int w = whalf * 32 + p * 16 + lr;
      float v1f = (float)(p ? v1i1 : v1i0) * sSC[576];
      float v3f = (float)(p ? v3i1 : v3i0) * sSC[577];
      float v4f = (float)(p ? v4i1 : v4i0) * sSC[578];
      float m6f = (float)(p ? m6i1 : m6i0) * sSC[512 + w];
      float S1 = v1f + qbs;
      float S2 = (p ? S21 : S20);
      float S3 = v3f + qggs;
      float S4 = v4f + qgbs;
      float S5 = (p ? S51 : S50);
      float S6 = m6f + QC[(size_t)n * NWC + w] + c3v[w];
      float mu2 = S1 * (1.0f / 512.0f);
      float var2 = S2 * (1.0f / 512.0f) - mu2 * mu2;
      float rs2 = rsqrtf(var2 + 1e-5f);
      float n2 = rs2 * rs2 * (S5 - 2.f * mu2 * S3 + mu2 * mu2 * sg2v)
               + 2.f * rs2 * (S4 - mu2 * sgbv) + sb2v;
      float num = rs2 * (S6 - mu2 * c1v[w]) + c2v[w];
      out[(size_t)n * NWC + w] = 16.0f * num / fmaxf(sqrtf(fmaxf(n2, 0.f)), 1e-12f);
    }
  }
}

// ---------------- launch ----------------

extern "C" void kernel_launch(void* const* d_in, const int* in_sizes, int n_in,
                              void* d_out, int out_size, void* d_ws, size_t ws_size,
                              hipStream_t stream) {
  const float* q    = (const float*)d_in[0];
  const float* cm   = (const float*)d_in[1];
  const float* ln1w = (const float*)d_in[2];
  const float* ln1b = (const float*)d_in[3];
  const float* w1   = (const float*)d_in[4];
  const float* b1   = (const float*)d_in[5];
  const float* w2   = (const float*)d_in[6];
  const float* b2   = (const float*)d_in[7];
  const float* ln2w = (const float*)d_in[8];
  const float* ln2b = (const float*)d_in[9];
  float* out = (float*)d_out;

  char* p = (char*)d_ws;
  auto alloc = [&](size_t bytes) { char* r = p; p += (bytes + 255) & ~(size_t)255; return r; };
  float* A     = (float*)alloc((size_t)NQ * DD * 4);
  unsigned short* Bwb = (unsigned short*)alloc((size_t)NWC * DD * 2);
  float* G     = (float*)alloc(DD * 4);
  float* C     = (float*)alloc(DD * 4);
  float* Gp    = (float*)alloc((size_t)16 * DD * 4);
  float* Cp    = (float*)alloc((size_t)16 * DD * 4);
  float* Sq    = (float*)alloc(NQ * 4);
  float* SSq   = (float*)alloc(NQ * 4);
  float* Sc    = (float*)alloc(NWC * 4);
  float* SSc   = (float*)alloc(NWC * 4);
  float* cmhg  = (float*)alloc((size_t)NWC * DD * 4);
  float* c1    = (float*)alloc(NWC * 4);
  float* c2    = (float*)alloc(NWC * 4);
  float* c3    = (float*)alloc(NWC * 4);
  float* gg    = (float*)alloc(DD * 4);
  float* scal  = (float*)alloc(256);
  float* qst   = (float*)alloc((size_t)NQ * 4 * 4);
  float* QC    = (float*)alloc((size_t)NQ * NWC * 4);
  float* M6buf = (float*)alloc((size_t)DD * NWC * 4);
  float* Vbuf  = (float*)alloc((size_t)DD * 4 * 4);
  float* Scl   = (float*)alloc(608 * 4);
  unsigned short* PW1T = (unsigned short*)alloc((size_t)DD * DD * 2);
  unsigned short* PW1B = (unsigned short*)alloc((size_t)DD * DD * 2);
  unsigned short* PCT  = (unsigned short*)alloc((size_t)DD * NWC * 2);
  unsigned short* PBw  = (unsigned short*)alloc((size_t)NWC * DD * 2);
  signed char* PW2X    = (signed char*)alloc((size_t)38 * 8192);

  k_prep<<<401, 256, 0, stream>>>(q, cm, ln1w, ln1b, w1, w2, ln2w, ln2b, b2,
                                  Sq, SSq, qst, Sc, SSc, cmhg, c1, c2, c3,
                                  Gp, Cp, Vbuf, gg, scal);
  k_pack1<<<136, 512, 0, stream>>>(w1, ln1w, cmhg, PW1T, PW1B, PCT);
  k_gemms<<<304, 256, 0, stream>>>(q, cm, w2, PW1T, PW1B, PCT, A, Bwb, QC, M6buf);
  k_pack2<<<43, 512, 0, stream>>>(w2, M6buf, Vbuf, Bwb, Gp, Cp, b1, PW2X, PBw, G, C, Scl);
  k_main<<<512, 512, 0, stream>>>(A, PBw, G, C, q, b2, gg, qst, QC, c1, c2, c3,
                                  Sq, SSq, Sc, SSc, scal, PW2X, Scl, out);
}

// Round 12
// 117.592 us; speedup vs baseline: 1.2397x; 1.0008x over previous
//
#include <hip/hip_runtime.h>
#include <cstdint>
#include <cstddef>

// ---------------------------------------------------------------------------
// HierarchicalQueryMatcher, N=2048, W=64, D=512.
//   LN1(x)@w1+b1 = rs*(A[n,:]+B[w,:]) - rs*mu*G + C
//   h2 = gelu(h) @ w2 ; y = h2 + q[n] + b2
//   out = 16 * dot(LN2(y), cmhat)/max(||LN2(y)||,eps)
// Linear-in-h2 sums folded into extra GEMM cols (M6 = w2@cmhg^T, v1,v3,v4);
// quadratic sums (S2,S5) streamed in the MFMA epilogue. h2-GEMM in INT8.
// Round 11 = r6 anchor (118us) + __launch_bounds__(512,4): force unified
// regs <= 128/wave so TWO 8-wave blocks fit per CU (LDS 74KB x2 <= 160KB).
// Occupancy 2 -> 4 waves/SIMD; the three half-idle pipes (VALU/LDS/MFMA)
// co-schedule across 2x the waves (m114). quad_i8 + fmed3 micro-opts kept.
// ---------------------------------------------------------------------------

#define NQ 2048
#define NWC 64
#define DD 512
#define NCHUNK 19
#define SA_CONST (4.0f / 127.0f)
#define MAGICF 12582912.0f

typedef __attribute__((ext_vector_type(8))) short short8;
typedef __attribute__((ext_vector_type(8))) unsigned short ushort8;
typedef __attribute__((ext_vector_type(4))) float f32x4;
typedef __attribute__((ext_vector_type(4))) int i32v4;
typedef __attribute__((ext_vector_type(4))) unsigned u32x4;

__device__ __forceinline__ unsigned short f2bf(float f) {
  unsigned u = __float_as_uint(f);
  u += 0x7fffu + ((u >> 16) & 1u);
  return (unsigned short)(u >> 16);
}

__device__ __forceinline__ unsigned cvtpk2(float lo, float hi) {
  unsigned r;
  asm("v_cvt_pk_bf16_f32 %0, %1, %2" : "=v"(r) : "v"(lo), "v"(hi));
  return r;
}

__device__ __forceinline__ float bf2f(unsigned short u) {
  return __uint_as_float(((unsigned)u) << 16);
}

// gelu(h)*31.75, clamped to [-127,127] via med3.
__device__ __forceinline__ float gelu31(float h) {
  float h2 = h * h;
  float zn = h * fmaf(h2, -0.10295890518f, -2.30221607f); // -z*log2(e)
  float t = exp2f(zn);
  float r = __builtin_amdgcn_rcpf(1.0f + t);
  float gv = (h * 31.75f) * r;
  return __builtin_amdgcn_fmed3f(gv, -127.0f, 127.0f);
}

// 4 clamped floats -> packed i8 dword via magic-round + byte_perm (7 ops).
__device__ __forceinline__ unsigned quad_i8(float a, float b, float c, float d) {
  unsigned u0 = __float_as_uint(a + MAGICF);
  unsigned u1 = __float_as_uint(b + MAGICF);
  unsigned u2 = __float_as_uint(c + MAGICF);
  unsigned u3 = __float_as_uint(d + MAGICF);
  unsigned s1 = __byte_perm(u0, u1, 0x0040);
  unsigned s2 = __byte_perm(u2, u3, 0x0040);
  return __byte_perm(s1, s2, 0x5410);
}

__device__ __forceinline__ float wred(float v) {
#pragma unroll
  for (int m = 1; m < 64; m <<= 1) v += __shfl_xor(v, m, 64);
  return v;
}

__device__ __forceinline__ int sel4i(i32v4 v, int r) {
  int x = (r & 1) ? v[1] : v[0];
  int y = (r & 1) ? v[3] : v[2];
  return (r & 2) ? y : x;
}

// ---------------- k_prep: all O(N*D) precompute in one launch ----------------
__global__ __launch_bounds__(256) void k_prep(
    const float* __restrict__ q, const float* __restrict__ cm,
    const float* __restrict__ g1, const float* __restrict__ be1,
    const float* __restrict__ w1, const float* __restrict__ w2,
    const float* __restrict__ g2, const float* __restrict__ be2,
    const float* __restrict__ b2,
    float* __restrict__ Sq, float* __restrict__ SSq, float* __restrict__ qst,
    float* __restrict__ Sc, float* __restrict__ SSc, float* __restrict__ cmhg,
    float* __restrict__ c1, float* __restrict__ c2, float* __restrict__ c3,
    float* __restrict__ Gp, float* __restrict__ Cp, float* __restrict__ V,
    float* __restrict__ gg, float* __restrict__ scal) {
  const int b = blockIdx.x, tid = threadIdx.x;
  const int wv = tid >> 6, l = tid & 63;
  __shared__ float shr[3][4];
  __shared__ float s_inv;

  if (b < 256) {
    f32x4 b20 = *(const f32x4*)(b2 + l * 8);
    f32x4 b21 = *(const f32x4*)(b2 + l * 8 + 4);
    f32x4 g20 = *(const f32x4*)(g2 + l * 8);
    f32x4 g21 = *(const f32x4*)(g2 + l * 8 + 4);
    f32x4 e20 = *(const f32x4*)(be2 + l * 8);
    f32x4 e21 = *(const f32x4*)(be2 + l * 8 + 4);
#pragma unroll
    for (int rr = 0; rr < 2; ++rr) {
      int r = b * 8 + wv * 2 + rr;
      const float* row = q + (size_t)r * DD;
      f32x4 q0 = *(const f32x4*)(row + l * 8);
      f32x4 q1 = *(const f32x4*)(row + l * 8 + 4);
      float s0 = 0, s1 = 0, s2 = 0, s3 = 0, s4 = 0;
#pragma unroll
      for (int i = 0; i < 4; ++i) {
        float v = q0[i]; s0 += v; s1 = fmaf(v, v, s1);
        float qb = v + b20[i], g = g20[i];
        s2 += qb; s3 = fmaf(qb, g * g, s3); s4 = fmaf(qb, g * e20[i], s4);
        v = q1[i]; s0 += v; s1 = fmaf(v, v, s1);
        qb = v + b21[i]; g = g21[i];
        s2 += qb; s3 = fmaf(qb, g * g, s3); s4 = fmaf(qb, g * e21[i], s4);
      }
      s0 = wred(s0); s1 = wred(s1); s2 = wred(s2); s3 = wred(s3); s4 = wred(s4);
      if (l == 0) {
        Sq[r] = s0; SSq[r] = s1;
        qst[r * 4 + 0] = s2; qst[r * 4 + 1] = s3; qst[r * 4 + 2] = s4;
      }
    }
  } else if (b < 320) {
    int w = b - 256;
    const float* row = cm + (size_t)w * DD;
    float sm = 0.f, ss = 0.f;
    for (int c = tid; c < DD; c += 256) { float v = row[c]; sm += v; ss = fmaf(v, v, ss); }
    sm = wred(sm); ss = wred(ss);
    if (l == 0) { shr[0][wv] = sm; shr[1][wv] = ss; }
    __syncthreads();
    if (tid == 0) {
      float smt = shr[0][0] + shr[0][1] + shr[0][2] + shr[0][3];
      float sst = shr[1][0] + shr[1][1] + shr[1][2] + shr[1][3];
      Sc[w] = smt; SSc[w] = sst;
      s_inv = 1.0f / fmaxf(sqrtf(sst), 1e-12f);
    }
    __syncthreads();
    float inv = s_inv;
    float a = 0.f, bs = 0.f, d = 0.f;
    for (int c = tid; c < DD; c += 256) {
      float ch = row[c] * inv;
      float gv = g2[c];
      float gch = gv * ch;
      cmhg[(size_t)w * DD + c] = gch;
      a += gch;
      bs = fmaf(be2[c], ch, bs);
      d = fmaf(b2[c], gch, d);
    }
    a = wred(a); bs = wred(bs); d = wred(d);
    __syncthreads();
    if (l == 0) { shr[0][wv] = a; shr[1][wv] = bs; shr[2][wv] = d; }
    __syncthreads();
    if (tid == 0) {
      c1[w] = shr[0][0] + shr[0][1] + shr[0][2] + shr[0][3];
      c2[w] = shr[1][0] + shr[1][1] + shr[1][2] + shr[1][3];
      c3[w] = shr[2][0] + shr[2][1] + shr[2][2] + shr[2][3];
    }
  } else if (b < 336) {
    int bk = b - 320, k0 = bk * 64;
#pragma unroll
    for (int jh = 0; jh < 2; ++jh) {
      int j = tid + jh * 256;
      float g = 0.f, c = 0.f;
#pragma unroll 4
      for (int k = 0; k < 64; ++k) {
        float wv4 = w1[(size_t)(k0 + k) * DD + j];
        g = fmaf(g1[k0 + k], wv4, g);
        c = fmaf(be1[k0 + k], wv4, c);
      }
      Gp[(size_t)bk * DD + j] = g;
      Cp[(size_t)bk * DD + j] = c;
    }
  } else if (b < 400) {
    int bb = b - 336;
    f32x4 g20 = *(const f32x4*)(g2 + l * 8);
    f32x4 g21 = *(const f32x4*)(g2 + l * 8 + 4);
    f32x4 e20 = *(const f32x4*)(be2 + l * 8);
    f32x4 e21 = *(const f32x4*)(be2 + l * 8 + 4);
#pragma unroll
    for (int rr = 0; rr < 2; ++rr) {
      int k = bb * 8 + wv * 2 + rr;
      const float* row = w2 + (size_t)k * DD;
      f32x4 w0 = *(const f32x4*)(row + l * 8);
      f32x4 w1v = *(const f32x4*)(row + l * 8 + 4);
      float s1 = 0, s3 = 0, s4 = 0;
#pragma unroll
      for (int i = 0; i < 4; ++i) {
        float w = w0[i], g = g20[i];
        s1 += w; s3 = fmaf(w, g * g, s3); s4 = fmaf(w, g * e20[i], s4);
        w = w1v[i]; g = g21[i];
        s1 += w; s3 = fmaf(w, g * g, s3); s4 = fmaf(w, g * e21[i], s4);
      }
      s1 = wred(s1); s3 = wred(s3); s4 = wred(s4);
      if (l == 0) {
        V[k * 4 + 0] = s1; V[k * 4 + 1] = s3; V[k * 4 + 2] = s4; V[k * 4 + 3] = 0.f;
      }
    }
  } else {
    float a0 = 0, a1 = 0, a2 = 0;
    for (int c = tid; c < DD; c += 256) {
      float g = g2[c], be = be2[c];
      gg[c] = g * g;
      a0 = fmaf(g, g, a0); a1 = fmaf(g, be, a1); a2 = fmaf(be, be, a2);
    }
    a0 = wred(a0); a1 = wred(a1); a2 = wred(a2);
    if (l == 0) { shr[0][wv] = a0; shr[1][wv] = a1; shr[2][wv] = a2; }
    __syncthreads();
    if (tid == 0) {
      scal[0] = shr[0][0] + shr[0][1] + shr[0][2] + shr[0][3];
      scal[1] = shr[1][0] + shr[1][1] + shr[1][2] + shr[1][3];
      scal[2] = shr[2][0] + shr[2][1] + shr[2][2] + shr[2][3];
    }
  }
}

// ---------------- k_pack1: PW1T + PW1B + PCT (bf16 GEMM operands) -------------
__global__ __launch_bounds__(512) void k_pack1(
    const float* __restrict__ w1, const float* __restrict__ ln1w,
    const float* __restrict__ cmhg,
    unsigned short* __restrict__ PW1T, unsigned short* __restrict__ PW1B,
    unsigned short* __restrict__ PCT) {
  int b = blockIdx.x;
  if (b < 128) {
    int roff = (b < 64) ? 0 : 512;
    unsigned short* out = (b < 64) ? PW1T : PW1B;
    int tid = (b & 63) * 512 + threadIdx.x;
    int l = tid & 63, t = (tid >> 6) & 15, ct = tid >> 10, g = l >> 4;
    int col = (ct << 4) + (l & 15);
    ushort8 o;
#pragma unroll
    for (int i = 0; i < 8; ++i) {
      int k = t * 32 + g * 8 + i;
      o[i] = f2bf(w1[(size_t)(roff + k) * DD + col] * ln1w[roff + k]);
    }
    *(ushort8*)(out + (size_t)tid * 8) = o;
  } else {
    int tid = (b - 128) * 512 + threadIdx.x;
    int l = tid & 63, t = (tid >> 6) & 15, g = l >> 4;
    int col = ((tid >> 10) << 4) + (l & 15);
    ushort8 o;
#pragma unroll
    for (int i = 0; i < 8; ++i) {
      int k = t * 32 + g * 8 + i;
      o[i] = f2bf(cmhg[(size_t)col * DD + k]);
    }
    *(ushort8*)(PCT + (size_t)tid * 8) = o;
  }
}

// ---------------- k_gemms: 4 bf16 GEMM jobs in one dispatch -------------------
__global__ __launch_bounds__(256) void k_gemms(
    const float* __restrict__ q, const float* __restrict__ cm,
    const float* __restrict__ w2,
    const unsigned short* __restrict__ PW1T, const unsigned short* __restrict__ PW1B,
    const unsigned short* __restrict__ PCT,
    float* __restrict__ A, unsigned short* __restrict__ Bwb,
    float* __restrict__ QC, float* __restrict__ M6) {
  int b = blockIdx.x;
  const float* X; const unsigned short* PW; void* Out;
  int bx, by, ostride, obf;
  if (b < 256)      { X = q;  PW = PW1T; Out = A;    bx = b & 7;   by = b >> 3;  ostride = DD;  obf = 0; }
  else if (b < 264) { X = cm; PW = PW1B; Out = Bwb;  bx = b - 256; by = 0;       ostride = DD;  obf = 1; }
  else if (b < 296) { X = q;  PW = PCT;  Out = QC;   bx = 0;       by = b - 264; ostride = NWC; obf = 0; }
  else              { X = w2; PW = PCT;  Out = M6;   bx = 0;       by = b - 296; ostride = NWC; obf = 0; }

  int l = threadIdx.x & 63;
  int wv = threadIdx.x >> 6;
  int lr = l & 15, g = l >> 4;
  int r0 = by * 64 + wv * 16;
  int cb0 = bx * 4;
  f32x4 acc[4] = {{0,0,0,0},{0,0,0,0},{0,0,0,0},{0,0,0,0}};
  const float* xrow = X + (size_t)(r0 + lr) * DD;
#pragma unroll
  for (int t = 0; t < 16; ++t) {
    int kb = t * 32 + g * 8;
    f32x4 x0 = *(const f32x4*)(xrow + kb);
    f32x4 x1 = *(const f32x4*)(xrow + kb + 4);
    union { short8 s; unsigned u[4]; } af;
    af.u[0] = cvtpk2(x0[0], x0[1]);
    af.u[1] = cvtpk2(x0[2], x0[3]);
    af.u[2] = cvtpk2(x1[0], x1[1]);
    af.u[3] = cvtpk2(x1[2], x1[3]);
#pragma unroll
    for (int c = 0; c < 4; ++c) {
      short8 bf = *(const short8*)(PW + (size_t)(((cb0 + c) * 16 + t) * 64 + l) * 8);
      acc[c] = __builtin_amdgcn_mfma_f32_16x16x32_bf16(af.s, bf, acc[c], 0, 0, 0);
    }
  }
#pragma unroll
  for (int c = 0; c < 4; ++c)
#pragma unroll
    for (int r = 0; r < 4; ++r) {
      size_t idx = (size_t)(r0 + g * 4 + r) * ostride + (cb0 + c) * 16 + lr;
      float v = acc[c][r];
      if (obf) ((unsigned short*)Out)[idx] = f2bf(v);
      else     ((float*)Out)[idx] = v;
    }
}

// ---------------- k_pack2: i8 W2X + scales + PBw + G/C ------------------------
__global__ __launch_bounds__(512) void k_pack2(
    const float* __restrict__ w2, const float* __restrict__ M6,
    const float* __restrict__ V, const unsigned short* __restrict__ Bwb,
    const float* __restrict__ Gp, const float* __restrict__ Cp,
    const float* __restrict__ b1,
    signed char* __restrict__ PW2X, unsigned short* __restrict__ PBw,
    float* __restrict__ G, float* __restrict__ C, float* __restrict__ Scales) {
  int b = blockIdx.x, tx = threadIdx.x;
  __shared__ float red[16][33];
  __shared__ float sinv[16];
  if (b < 38) {
    int ct = b;
    int t8 = tx >> 6, l = tx & 63, g4 = l >> 4, lc = l & 15;
    int col = ct * 16 + lc;
    float v[16]; float lmax = 0.f;
#pragma unroll
    for (int i = 0; i < 16; ++i) {
      int k = t8 * 64 + g4 * 16 + i;
      float x;
      if (col < 512)      x = w2[(size_t)k * DD + col];
      else if (col < 576) x = M6[(size_t)k * 64 + (col - 512)];
      else { int cv = col - 576; x = (cv < 3) ? V[k * 4 + cv] : 0.f; }
      v[i] = x; lmax = fmaxf(lmax, fabsf(x));
    }
    red[lc][t8 * 4 + g4] = lmax;
    __syncthreads();
    if (tx < 16) {
      float m = 0.f;
#pragma unroll
      for (int j = 0; j < 32; ++j) m = fmaxf(m, red[tx][j]);
      float sc = fmaxf(m, 1e-20f) * (1.0f / 127.0f);
      Scales[ct * 16 + tx] = sc;
      sinv[tx] = 1.0f / sc;
    }
    __syncthreads();
    float inv = sinv[lc];
    u32x4 d;
#pragma unroll
    for (int j = 0; j < 4; ++j) {
      unsigned u = 0;
#pragma unroll
      for (int e = 0; e < 4; ++e) {
        float qv = v[j * 4 + e] * inv;
        qv = fminf(fmaxf(qv, -127.f), 127.f);
        int iq = (int)rintf(qv);
        u |= ((unsigned)(iq & 255)) << (8 * e);
      }
      d[j] = u;
    }
    *(u32x4*)(PW2X + (size_t)ct * 8192 + (size_t)(t8 * 64 + l) * 16) = d;
  } else if (b < 42) {
    int slot = (b - 38) * 512 + tx;  // 2048 slots
    int wt = slot >> 9, r = slot & 511, t8 = r >> 6, l = r & 63;
    int w = wt * 16 + (l & 15);
    int kb = t8 * 64 + (l >> 4) * 16;
    ushort8 o0, o1;
#pragma unroll
    for (int i = 0; i < 8; ++i) {
      o0[i] = Bwb[(size_t)w * DD + kb + i];
      o1[i] = Bwb[(size_t)w * DD + kb + 8 + i];
    }
    *(ushort8*)(PBw + (size_t)slot * 16) = o0;
    *(ushort8*)(PBw + (size_t)slot * 16 + 8) = o1;
  } else {
    int c = tx;
    float g = 0.f, cc2 = 0.f;
#pragma unroll
    for (int p = 0; p < 16; ++p) { g += Gp[p * DD + c]; cc2 += Cp[p * DD + c]; }
    G[c] = g; C[c] = cc2 + b1[c];
  }
}

// ---------------- fused main kernel: i8 GEMM, counted-vmcnt 3-ring ------------

__device__ __forceinline__ void async16(const void* g, void* lds) {
  __builtin_amdgcn_global_load_lds(
      (const __attribute__((address_space(1))) void*)(uintptr_t)g,
      (__attribute__((address_space(3))) void*)(unsigned int)(uintptr_t)lds,
      16, 0, 0);
}

__global__ __launch_bounds__(512, 4) void k_main(
    const float* __restrict__ Afull, const unsigned short* __restrict__ PBw,
    const float* __restrict__ G, const float* __restrict__ Cc,
    const float* __restrict__ q, const float* __restrict__ b2,
    const float* __restrict__ gg, const float* __restrict__ qst,
    const float* __restrict__ QC, const float* __restrict__ c1v,
    const float* __restrict__ c2v, const float* __restrict__ c3v,
    const float* __restrict__ Sq, const float* __restrict__ SSq,
    const float* __restrict__ Sc, const float* __restrict__ SSc,
    const float* __restrict__ scal, const signed char* __restrict__ PW2X,
    const float* __restrict__ Scales, float* __restrict__ out) {

  __shared__ __align__(16) float sG[DD], sC[DD], sGG[DD], sSC[608];
  __shared__ __align__(16) float sA[4][DD], sQB[4][DD];
  __shared__ __align__(16) signed char sW[3 * 16384];   // 3x16KB i8 chunk ring

  const int tid = threadIdx.x;
  const int wv = tid >> 6, l = tid & 63;
  const int g = l >> 4, lr = l & 15;
  const int n0 = blockIdx.x * 4;
  const int sub = wv >> 1;             // which n of the 4
  const int n = n0 + sub;
  const int whalf = wv & 1;
  const int w0 = whalf * 32 + lr;
  const int w1p = w0 + 16;

  // ---- stage block-wide LDS state ----
  sG[tid] = G[tid]; sC[tid] = Cc[tid]; sGG[tid] = gg[tid];
  for (int i = tid; i < 608; i += 512) sSC[i] = Scales[i] * SA_CONST;
#pragma unroll
  for (int s = 0; s < 4; ++s) {
    sA[s][tid]  = Afull[(size_t)(n0 + s) * DD + tid];
    sQB[s][tid] = q[(size_t)(n0 + s) * DD + tid] + b2[tid];
  }
  __syncthreads();

  // prefetch chunks 0,1 (hidden under the gelu phase). 2 loads/thread/chunk.
#pragma unroll
  for (int c = 0; c < 2; ++c)
#pragma unroll
    for (int j = 0; j < 2; ++j)
      async16(PW2X + (size_t)c * 16384 + (size_t)(j * 512 + tid) * 16,
              &sW[c * 16384 + (j * 512 + wv * 64) * 16]);

  // ---- LN1 scalars for this lane's two (n,w) pairs ----
  float sqn = Sq[n], ssqn = SSq[n];
  float mu0 = (sqn + Sc[w0]) * (1.0f / 1024.0f);
  float rs0 = rsqrtf((ssqn + SSc[w0]) * (1.0f / 1024.0f) - mu0 * mu0 + 1e-5f);
  float mu1 = (sqn + Sc[w1p]) * (1.0f / 1024.0f);
  float rs1 = rsqrtf((ssqn + SSc[w1p]) * (1.0f / 1024.0f) - mu1 * mu1 + 1e-5f);
  float al0 = rs0, bl0 = -rs0 * mu0;
  float al1 = rs1, bl1 = -rs1 * mu1;

  // ---- gelu fragments -> i8 MFMA B-operand layout (k = t8*64 + g*16 + i) ----
  i32v4 af0[8], af1[8];
  const unsigned short* pb0 = PBw + (size_t)(whalf * 2) * 8192;
  const unsigned short* pb1 = PBw + (size_t)(whalf * 2 + 1) * 8192;
#pragma unroll
  for (int t8 = 0; t8 < 8; ++t8) {
    int kb = t8 * 64 + g * 16;
    ushort8 u0a = *(const ushort8*)(pb0 + (size_t)(t8 * 64 + l) * 16);
    ushort8 u0b = *(const ushort8*)(pb0 + (size_t)(t8 * 64 + l) * 16 + 8);
    ushort8 u1a = *(const ushort8*)(pb1 + (size_t)(t8 * 64 + l) * 16);
    ushort8 u1b = *(const ushort8*)(pb1 + (size_t)(t8 * 64 + l) * 16 + 8);
    unsigned dw0[4], dw1[4];
#pragma unroll
    for (int j = 0; j < 4; ++j) {
      f32x4 av = *(const f32x4*)&sA[sub][kb + j * 4];
      f32x4 gv = *(const f32x4*)&sG[kb + j * 4];
      f32x4 cv = *(const f32x4*)&sC[kb + j * 4];
      float hA[4], hB[4];
#pragma unroll
      for (int i2 = 0; i2 < 4; ++i2) {
        int e = j * 4 + i2;
        float bw0 = bf2f(e < 8 ? u0a[e & 7] : u0b[e & 7]);
        float bw1 = bf2f(e < 8 ? u1a[e & 7] : u1b[e & 7]);
        float base0 = fmaf(bl0, gv[i2], cv[i2]);
        float base1 = fmaf(bl1, gv[i2], cv[i2]);
        hA[i2] = gelu31(fmaf(al0, av[i2] + bw0, base0));
        hB[i2] = gelu31(fmaf(al1, av[i2] + bw1, base1));
      }
      dw0[j] = quad_i8(hA[0], hA[1], hA[2], hA[3]);
      dw1[j] = quad_i8(hB[0], hB[1], hB[2], hB[3]);
    }
    i32v4 a0v = {(int)dw0[0], (int)dw0[1], (int)dw0[2], (int)dw0[3]};
    i32v4 a1v = {(int)dw1[0], (int)dw1[1], (int)dw1[2], (int)dw1[3]};
    af0[t8] = a0v; af1[t8] = a1v;
  }

  float S20 = 0.f, S50 = 0.f, S21 = 0.f, S51 = 0.f;
  int m6i0 = 0, m6i1 = 0;
  int v1i0 = 0, v3i0 = 0, v4i0 = 0;
  int v1i1 = 0, v3i1 = 0, v4i1 = 0;

#pragma unroll 1
  for (int cc = 0; cc < NCHUNK; ++cc) {
    // counted waits: chunk cc landed; cc+1's 2 loads stay in flight.
    if (cc < NCHUNK - 1) asm volatile("s_waitcnt vmcnt(2)" ::: "memory");
    else                 asm volatile("s_waitcnt vmcnt(0)" ::: "memory");
    asm volatile("s_waitcnt lgkmcnt(0)" ::: "memory");
    __builtin_amdgcn_s_barrier();
    if (cc + 2 < NCHUNK) {             // prefetch depth 2 into ring slot
      const signed char* src = PW2X + (size_t)(cc + 2) * 16384;
      signed char* dst = &sW[((cc + 2) % 3) * 16384];
#pragma unroll
      for (int j = 0; j < 2; ++j)
        async16(src + (size_t)(j * 512 + tid) * 16, dst + (j * 512 + wv * 64) * 16);
    }
    const signed char* wbuf = &sW[(cc % 3) * 16384];

    if (cc < 16) {
      i32v4 acc00 = {0,0,0,0}, acc01 = {0,0,0,0}, acc10 = {0,0,0,0}, acc11 = {0,0,0,0};
      __builtin_amdgcn_s_setprio(1);
#pragma unroll
      for (int t8 = 0; t8 < 8; ++t8) {
        i32v4 bf0 = *(const i32v4*)(wbuf + (size_t)(t8 * 64 + l) * 16);
        i32v4 bf1 = *(const i32v4*)(wbuf + 8192 + (size_t)(t8 * 64 + l) * 16);
        acc00 = __builtin_amdgcn_mfma_i32_16x16x64_i8(bf0, af0[t8], acc00, 0, 0, 0);
        acc10 = __builtin_amdgcn_mfma_i32_16x16x64_i8(bf0, af1[t8], acc10, 0, 0, 0);
        acc01 = __builtin_amdgcn_mfma_i32_16x16x64_i8(bf1, af0[t8], acc01, 0, 0, 0);
        acc11 = __builtin_amdgcn_mfma_i32_16x16x64_i8(bf1, af1[t8], acc11, 0, 0, 0);
      }
      __builtin_amdgcn_s_setprio(0);
#pragma unroll
      for (int ct = 0; ct < 2; ++ct) {
        int cb = cc * 32 + ct * 16 + g * 4;
        f32x4 qb4 = *(const f32x4*)&sQB[sub][cb];
        f32x4 gg4 = *(const f32x4*)&sGG[cb];
        f32x4 sc4 = *(const f32x4*)&sSC[cb];
        i32v4 aAv = ct ? acc01 : acc00;
        i32v4 aBv = ct ? acc11 : acc10;
#pragma unroll
        for (int r = 0; r < 4; ++r) {
          float y = fmaf((float)aAv[r], sc4[r], qb4[r]);
          float y2 = y * y;
          S20 += y2; S50 = fmaf(y2, gg4[r], S50);
          float z = fmaf((float)aBv[r], sc4[r], qb4[r]);
          float z2 = z * z;
          S21 += z2; S51 = fmaf(z2, gg4[r], S51);
        }
      }
    } else if (cc == 16 || cc == 17) {
      if (cc == 16 + whalf) {
        i32v4 acc00 = {0,0,0,0}, acc11 = {0,0,0,0};
        __builtin_amdgcn_s_setprio(1);
#pragma unroll
        for (int t8 = 0; t8 < 8; ++t8) {
          i32v4 bf0 = *(const i32v4*)(wbuf + (size_t)(t8 * 64 + l) * 16);
          i32v4 bf1 = *(const i32v4*)(wbuf + 8192 + (size_t)(t8 * 64 + l) * 16);
          acc00 = __builtin_amdgcn_mfma_i32_16x16x64_i8(bf0, af0[t8], acc00, 0, 0, 0);
          acc11 = __builtin_amdgcn_mfma_i32_16x16x64_i8(bf1, af1[t8], acc11, 0, 0, 0);
        }
        __builtin_amdgcn_s_setprio(0);
        int d0 = sel4i(acc00, lr & 3);
        int d1 = sel4i(acc11, lr & 3);
        int src = lr + ((lr >> 2) << 4);
        m6i0 = __shfl(d0, src, 64);
        m6i1 = __shfl(d1, src, 64);
      }
    } else {
      i32v4 acc00 = {0,0,0,0}, acc10 = {0,0,0,0};
      __builtin_amdgcn_s_setprio(1);
#pragma unroll
      for (int t8 = 0; t8 < 8; ++t8) {
        i32v4 bf0 = *(const i32v4*)(wbuf + (size_t)(t8 * 64 + l) * 16);
        acc00 = __builtin_amdgcn_mfma_i32_16x16x64_i8(bf0, af0[t8], acc00, 0, 0, 0);
        acc10 = __builtin_amdgcn_mfma_i32_16x16x64_i8(bf0, af1[t8], acc10, 0, 0, 0);
      }
      __builtin_amdgcn_s_setprio(0);
      v1i0 = __shfl(acc00[0], lr, 64);
      v3i0 = __shfl(acc00[1], lr, 64);
      v4i0 = __shfl(acc00[2], lr, 64);
      v1i1 = __shfl(acc10[0], lr, 64);
      v3i1 = __shfl(acc10[1], lr, 64);
      v4i1 = __shfl(acc10[2], lr, 64);
    }
  }

  S20 += __shfl_xor(S20, 16, 64); S20 += __shfl_xor(S20, 32, 64);
  S50 += __shfl_xor(S50, 16, 64); S50 += __shfl_xor(S50, 32, 64);
  S21 += __shfl_xor(S21, 16, 64); S21 += __shfl_xor(S21, 32, 64);
  S51 += __shfl_xor(S51, 16, 64); S51 += __shfl_xor(S51, 32, 64);

  if (g == 0) {
    float sg2v = scal[0], sgbv = scal[1], sb2v = scal[2];
    float qbs = qst[n * 4 + 0], qggs = qst[n * 4 + 1], qgbs = qst[n * 4 + 2];
#pragma unroll
    for (int p = 0; p < 2; ++p) {
      int w = whalf * 32 + p * 16 + lr;
      float v1f = (float)(p ? v1i1 : v1i0) * sSC[576];
      float v3f = (float)(p ? v3i1 : v3i0) * sSC[577];
      float v4f = (float)(p ? v4i1 : v4i0) * sSC[578];
      float m6f = (float)(p ? m6i1 : m6i0) * sSC[512 + w];
      float S1 = v1f + qbs;
      float S2 = (p ? S21 : S20);
      float S3 = v3f + qggs;
      float S4 = v4f + qgbs;
      float S5 = (p ? S51 : S50);
      float S6 = m6f + QC[(size_t)n * NWC + w] + c3v[w];
      float mu2 = S1 * (1.0f / 512.0f);
      float var2 = S2 * (1.0f / 512.0f) - mu2 * mu2;
      float rs2 = rsqrtf(var2 + 1e-5f);
      float n2 = rs2 * rs2 * (S5 - 2.f * mu2 * S3 + mu2 * mu2 * sg2v)
               + 2.f * rs2 * (S4 - mu2 * sgbv) + sb2v;
      float num = rs2 * (S6 - mu2 * c1v[w]) + c2v[w];
      out[(size_t)n * NWC + w] = 16.0f * num / fmaxf(sqrtf(fmaxf(n2, 0.f)), 1e-12f);
    }
  }
}

// ---------------- launch ----------------

extern "C" void kernel_launch(void* const* d_in, const int* in_sizes, int n_in,
                              void* d_out, int out_size, void* d_ws, size_t ws_size,
                              hipStream_t stream) {
  const float* q    = (const float*)d_in[0];
  const float* cm   = (const float*)d_in[1];
  const float* ln1w = (const float*)d_in[2];
  const float* ln1b = (const float*)d_in[3];
  const float* w1   = (const float*)d_in[4];
  const float* b1   = (const float*)d_in[5];
  const float* w2   = (const float*)d_in[6];
  const float* b2   = (const float*)d_in[7];
  const float* ln2w = (const float*)d_in[8];
  const float* ln2b = (const float*)d_in[9];
  float* out = (float*)d_out;

  char* p = (char*)d_ws;
  auto alloc = [&](size_t bytes) { char* r = p; p += (bytes + 255) & ~(size_t)255; return r; };
  float* A     = (float*)alloc((size_t)NQ * DD * 4);
  unsigned short* Bwb = (unsigned short*)alloc((size_t)NWC * DD * 2);
  float* G     = (float*)alloc(DD * 4);
  float* C     = (float*)alloc(DD * 4);
  float* Gp    = (float*)alloc((size_t)16 * DD * 4);
  float* Cp    = (float*)alloc((size_t)16 * DD * 4);
  float* Sq    = (float*)alloc(NQ * 4);
  float* SSq   = (float*)alloc(NQ * 4);
  float* Sc    = (float*)alloc(NWC * 4);
  float* SSc   = (float*)alloc(NWC * 4);
  float* cmhg  = (float*)alloc((size_t)NWC * DD * 4);
  float* c1    = (float*)alloc(NWC * 4);
  float* c2    = (float*)alloc(NWC * 4);
  float* c3    = (float*)alloc(NWC * 4);
  float* gg    = (float*)alloc(DD * 4);
  float* scal  = (float*)alloc(256);
  float* qst   = (float*)alloc((size_t)NQ * 4 * 4);
  float* QC    = (float*)alloc((size_t)NQ * NWC * 4);
  float* M6buf = (float*)alloc((size_t)DD * NWC * 4);
  float* Vbuf  = (float*)alloc((size_t)DD * 4 * 4);
  float* Scl   = (float*)alloc(608 * 4);
  unsigned short* PW1T = (unsigned short*)alloc((size_t)DD * DD * 2);
  unsigned short* PW1B = (unsigned short*)alloc((size_t)DD * DD * 2);
  unsigned short* PCT  = (unsigned short*)alloc((size_t)DD * NWC * 2);
  unsigned short* PBw  = (unsigned short*)alloc((size_t)NWC * DD * 2);
  signed char* PW2X    = (signed char*)alloc((size_t)38 * 8192);

  k_prep<<<401, 256, 0, stream>>>(q, cm, ln1w, ln1b, w1, w2, ln2w, ln2b, b2,
                                  Sq, SSq, qst, Sc, SSc, cmhg, c1, c2, c3,
                                  Gp, Cp, Vbuf, gg, scal);
  k_pack1<<<136, 512, 0, stream>>>(w1, ln1w, cmhg, PW1T, PW1B, PCT);
  k_gemms<<<304, 256, 0, stream>>>(q, cm, w2, PW1T, PW1B, PCT, A, Bwb, QC, M6buf);
  k_pack2<<<43, 512, 0, stream>>>(w2, M6buf, Vbuf, Bwb, Gp, Cp, b1, PW2X, PBw, G, C, Scl);
  k_main<<<512, 512, 0, stream>>>(A, PBw, G, C, q, b2, gg, qst, QC, c1, c2, c3,
                                  Sq, SSq, Sc, SSc, scal, PW2X, Scl, out);
}